// Round 16
// baseline (718.099 us; speedup 1.0000x reference)
//
#include <hip/hip_runtime.h>
#include <hip/hip_cooperative_groups.h>
#include <math.h>

namespace cg = cooperative_groups;

constexpr int Bn  = 16;
constexpr int Sn  = 512;
constexpr int S2n = 64;
constexpr int Hn  = 128;
constexpr int Ln  = 3;
constexpr int NNZ_CAP = 128;

#define TID ((int)threadIdx.x)

typedef __attribute__((ext_vector_type(8))) short bf16x8;
typedef __attribute__((ext_vector_type(4))) float f32x4;

__device__ inline float wave_reduce_sum(float v) {
#pragma unroll
  for (int off = 32; off > 0; off >>= 1) v += __shfl_xor(v, off, 64);
  return v;
}

__device__ inline float block_reduce_sum(float v, float* red) {
  v = wave_reduce_sum(v);
  int w  = TID >> 6;
  int nw = (int)blockDim.x >> 6;
  if ((TID & 63) == 0) red[w] = v;
  __syncthreads();
  float s = 0.f;
  for (int i = 0; i < nw; ++i) s += red[i];
  __syncthreads();
  return s;
}

__device__ inline float sigm(float x) { return 1.f / (1.f + expf(-x)); }

__device__ inline unsigned short f2bf(float f) {
  unsigned int u = __float_as_uint(f);
  u = (u + 0x7fffu + ((u >> 16) & 1u)) >> 16;
  return (unsigned short)u;
}

struct SmP  { float t[32][33]; };
struct SmQ  { float Ws[2][128]; float bns[128]; float red[4]; };
struct SmB  { float Xs[16 * 128]; };
struct SmA  { float qs[32][132]; float ks[32][132]; float w2s[128]; float es[32][33]; };
struct SmFG { float Es[2][512]; float red[4]; float acts[2][128]; float sfs[2][128]; float redl[4]; };
union Smem  { SmP p; SmQ q; SmB b; SmA a; SmFG fg; float red4[4]; };

struct MegaArgs {
  const float *states, *actions, *am, *sm, *adj;
  const float *Wn, *bn, *Wu, *bu, *Wr, *br, *Wt, *bt, *Wa1, *ba1, *Wa2, *ba2;
  const float *Wv, *bv, *weight, *bias;
  float *h, *g, *zp, *rh, *kp, *qp, *E, *sfb, *adv;
  float *WtRT, *Wa1T, *cu, *cr, *ct;
  short *Bp;
  unsigned short *idx;
  int *cnts;
  float *outq;
};

__device__ void tile_gemm128(const float* __restrict__ Xsrc,
                             const float* __restrict__ WT,
                             const float* __restrict__ bias,
                             float* __restrict__ Y, int r0, float* Xs)
{
  const float* xsrc = Xsrc + (size_t)r0 * 128;
  for (int i = TID; i < 512; i += 256)
    ((float4*)Xs)[i] = ((const float4*)xsrc)[i];
  __syncthreads();
  int c4 = (TID & 31) * 4;
  int rb = (TID >> 5) * 2;
  float acc[2][4] = {};
#pragma unroll 4
  for (int k = 0; k < 128; k += 4) {
    const float* wk = WT + (size_t)k * 128 + c4;
    float4 w0 = *(const float4*)(wk);
    float4 w1 = *(const float4*)(wk + 128);
    float4 w2 = *(const float4*)(wk + 256);
    float4 w3 = *(const float4*)(wk + 384);
#pragma unroll
    for (int r = 0; r < 2; ++r) {
      float4 x = *(const float4*)&Xs[(rb + r) * 128 + k];
      acc[r][0] = fmaf(x.x, w0.x, acc[r][0]); acc[r][0] = fmaf(x.y, w1.x, acc[r][0]);
      acc[r][0] = fmaf(x.z, w2.x, acc[r][0]); acc[r][0] = fmaf(x.w, w3.x, acc[r][0]);
      acc[r][1] = fmaf(x.x, w0.y, acc[r][1]); acc[r][1] = fmaf(x.y, w1.y, acc[r][1]);
      acc[r][1] = fmaf(x.z, w2.y, acc[r][1]); acc[r][1] = fmaf(x.w, w3.y, acc[r][1]);
      acc[r][2] = fmaf(x.x, w0.z, acc[r][2]); acc[r][2] = fmaf(x.y, w1.z, acc[r][2]);
      acc[r][2] = fmaf(x.z, w2.z, acc[r][2]); acc[r][2] = fmaf(x.w, w3.z, acc[r][2]);
      acc[r][3] = fmaf(x.x, w0.w, acc[r][3]); acc[r][3] = fmaf(x.y, w1.w, acc[r][3]);
      acc[r][3] = fmaf(x.z, w2.w, acc[r][3]); acc[r][3] = fmaf(x.w, w3.w, acc[r][3]);
    }
  }
  float4 bv = {0.f, 0.f, 0.f, 0.f};
  if (bias) bv = *(const float4*)(bias + c4);
#pragma unroll
  for (int r = 0; r < 2; ++r) {
    float4 v = {acc[r][0] + bv.x, acc[r][1] + bv.y,
                acc[r][2] + bv.z, acc[r][3] + bv.w};
    *(float4*)(Y + (size_t)(r0 + rb + r) * 128 + c4) = v;
  }
  __syncthreads();
}

__global__ __launch_bounds__(256) void mega(MegaArgs A)
{
  cg::grid_group gr = cg::this_grid();
  __shared__ Smem sm;
  const int t = TID, bid = blockIdx.x;
  const int G = (int)gridDim.x;
  const int lane = t & 63, wv = t >> 6;

  // ---- phase 0: adjacency compaction + transposes + combine/pack ----
  for (int vb = bid; vb < 2288; vb += G) {
    if (vb < 2048) {
      int row = vb * 4 + wv;
      const float* ar = A.adj + (size_t)row * Sn;
      unsigned short* out = A.idx + (size_t)row * NNZ_CAP;
      int base = 0;
      for (int j0 = 0; j0 < Sn; j0 += 64) {
        float av = ar[j0 + lane];
        unsigned long long m = __ballot(av != 0.f);
        int pos = __popcll(m & ((1ull << lane) - 1ull));
        if (av != 0.f) out[base + pos] = (unsigned short)(j0 + lane);
        base += __popcll(m);
      }
      if (lane == 0) A.cnts[row] = base;
    } else if (vb < 2096) {
      int flat = vb - 2048;
      const float* src; float* dst; int k0, n0, woff;
      if (flat < 16) { src = A.Wt;  dst = A.WtRT; k0 = (flat & 3) * 32; n0 = (flat >> 2) * 32; woff = 128; }
      else { int f2 = flat - 16; src = A.Wa1; dst = A.Wa1T; k0 = (f2 & 7) * 32; n0 = (f2 >> 3) * 32; woff = 0; }
      int tx = t & 31, ty = t >> 5;
#pragma unroll
      for (int i = 0; i < 32; i += 8)
        sm.p.t[ty + i][tx] = src[(size_t)(n0 + ty + i) * 256 + woff + k0 + tx];
      __syncthreads();
#pragma unroll
      for (int i = 0; i < 32; i += 8)
        dst[(size_t)(k0 + ty + i) * 128 + n0 + tx] = sm.p.t[tx][ty + i];
      __syncthreads();
    } else {
      int half = t >> 7, tloc = t & 127;
      int u = (vb - 2096) * 2 + half;
      int mat = u >> 7, n = u & 127;
      const float* W = (mat == 0) ? A.Wu : (mat == 1) ? A.Wr : A.Wt;
      float* cv = (mat == 0) ? A.cu : (mat == 1) ? A.cr : A.ct;
      sm.q.Ws[half][tloc] = W[(size_t)n * 256 + tloc];
      if (t < 128) sm.q.bns[t] = A.bn[t];
      __syncthreads();
      float acc = 0.f;
#pragma unroll 4
      for (int c = 0; c < 128; ++c)
        acc = fmaf(A.Wn[(size_t)c * 128 + tloc], sm.q.Ws[half][c], acc);
      if (mat < 2) acc += W[(size_t)n * 256 + 128 + tloc];
      int k = tloc;
      int id2 = ((mat * 8 + (n >> 4)) * 4 + (k >> 5)) * 512 +
                (((k & 31) >> 3) * 16 + (n & 15)) * 8 + (k & 7);
      A.Bp[id2] = (short)f2bf(acc);
      float pv = sm.q.bns[tloc] * sm.q.Ws[half][tloc];
      pv = wave_reduce_sum(pv);
      if (lane == 0) sm.q.red[wv] = pv;
      __syncthreads();
      if (tloc == 0) cv[n] = sm.q.red[half * 2] + sm.q.red[half * 2 + 1];
      __syncthreads();
    }
  }
  gr.sync();

  for (int step = 0; step < 3; ++step) {
    const float* hin = (step == 0) ? A.states : A.h;

    // phase A: g = h @ [Gu|Gr|Gt] via bf16 MFMA
    for (int vb = bid; vb < 384; vb += G) {
      int mat = vb >> 7, rt = vb & 127;
      int r0 = rt * 64 + wv * 16;
      const float* abase = hin + (size_t)(r0 + (lane & 15)) * 128 + (lane >> 4) * 8;
      bf16x8 a[4];
#pragma unroll
      for (int kc = 0; kc < 4; ++kc) {
        float4 f0 = *(const float4*)(abase + kc * 32);
        float4 f1 = *(const float4*)(abase + kc * 32 + 4);
        bf16x8 v;
        v[0] = (short)f2bf(f0.x); v[1] = (short)f2bf(f0.y);
        v[2] = (short)f2bf(f0.z); v[3] = (short)f2bf(f0.w);
        v[4] = (short)f2bf(f1.x); v[5] = (short)f2bf(f1.y);
        v[6] = (short)f2bf(f1.z); v[7] = (short)f2bf(f1.w);
        a[kc] = v;
      }
      f32x4 acc[8];
#pragma unroll
      for (int nt = 0; nt < 8; ++nt) acc[nt] = (f32x4){0.f, 0.f, 0.f, 0.f};
      const short* bbase = A.Bp + (size_t)(mat * 8) * 4 * 512 + lane * 8;
#pragma unroll
      for (int nt = 0; nt < 8; ++nt)
#pragma unroll
        for (int kc = 0; kc < 4; ++kc) {
          bf16x8 b = *(const bf16x8*)(bbase + (nt * 4 + kc) * 512);
          acc[nt] = __builtin_amdgcn_mfma_f32_16x16x32_bf16(a[kc], b, acc[nt], 0, 0, 0);
        }
      int col0 = lane & 15, rb2 = (lane >> 4) * 4;
      float* gout = A.g + (size_t)(r0 + rb2) * 384 + mat * 128 + col0;
#pragma unroll
      for (int nt = 0; nt < 8; ++nt) {
        float cadd = (mat == 2) ? A.ct[nt * 16 + col0] : 0.f;
#pragma unroll
        for (int r = 0; r < 4; ++r)
          gout[(size_t)r * 384 + nt * 16] = acc[nt][r] + cadd;
      }
    }
    gr.sync();

    // phase B: gates via compact-index gather
    for (int vb = bid; vb < 2048; vb += G) {
      int tile = vb & 127, b = vb >> 7;
      int i = tile * 4 + wv;
      size_t row = (size_t)b * Sn + i;
      int c  = (lane < 32) ? 4 * lane : 128 + 4 * (lane - 32);
      int cc = (lane < 32) ? 4 * lane : 4 * (lane - 32);
      const float* gb = A.g + (size_t)b * Sn * 384 + c;
      const unsigned short* ix = A.idx + row * NNZ_CAP;
      int cnt = A.cnts[row];
      float4 acc = {0.f, 0.f, 0.f, 0.f};
      int n = 0;
      for (; n + 4 <= cnt; n += 4) {
        ushort4 jj = *(const ushort4*)(ix + n);
        float4 x0 = *(const float4*)(gb + (size_t)jj.x * 384);
        float4 x1 = *(const float4*)(gb + (size_t)jj.y * 384);
        float4 x2 = *(const float4*)(gb + (size_t)jj.z * 384);
        float4 x3 = *(const float4*)(gb + (size_t)jj.w * 384);
        acc.x += (x0.x + x1.x) + (x2.x + x3.x);
        acc.y += (x0.y + x1.y) + (x2.y + x3.y);
        acc.z += (x0.z + x1.z) + (x2.z + x3.z);
        acc.w += (x0.w + x1.w) + (x2.w + x3.w);
      }
      for (; n < cnt; ++n) {
        int j = ix[n];
        float4 x = *(const float4*)(gb + (size_t)j * 384);
        acc.x += x.x; acc.y += x.y; acc.z += x.z; acc.w += x.w;
      }
      float d = (float)cnt;
      const float* cvp = (lane < 32) ? A.cu : A.cr;
      const float* bvp = (lane < 32) ? A.bu : A.br;
      float4 cv = *(const float4*)(cvp + cc);
      float4 bv = *(const float4*)(bvp + cc);
      float4 sg;
      sg.x = sigm(acc.x + d * cv.x + bv.x);
      sg.y = sigm(acc.y + d * cv.y + bv.y);
      sg.z = sigm(acc.z + d * cv.z + bv.z);
      sg.w = sigm(acc.w + d * cv.w + bv.w);
      if (lane < 32) {
        *(float4*)(A.zp + row * 128 + cc) = sg;
      } else {
        float4 hv = *(const float4*)(hin + row * 128 + cc);
        sg.x *= hv.x; sg.y *= hv.y; sg.z *= hv.z; sg.w *= hv.w;
        *(float4*)(A.rh + row * 128 + cc) = sg;
      }
    }
    gr.sync();

    // phase C: h update (+ kp epilogue + qp gemm on last step)
    int climit = (step == 2) ? 576 : 512;
    for (int vb = bid; vb < climit; vb += G) {
      if (vb < 512) {
        int r0 = vb * 16;
        float* Xs = sm.b.Xs;
        const float* xsrc = A.rh + (size_t)r0 * 128;
        for (int i = t; i < 512; i += 256)
          ((float4*)Xs)[i] = ((const float4*)xsrc)[i];
        __syncthreads();
        int c4 = (t & 31) * 4;
        int rb = (t >> 5) * 2;
        float acc[2][4] = {};
#pragma unroll 4
        for (int k = 0; k < 128; k += 4) {
          const float* wk = A.WtRT + (size_t)k * 128 + c4;
          float4 w0 = *(const float4*)(wk);
          float4 w1 = *(const float4*)(wk + 128);
          float4 w2 = *(const float4*)(wk + 256);
          float4 w3 = *(const float4*)(wk + 384);
#pragma unroll
          for (int r = 0; r < 2; ++r) {
            float4 x = *(const float4*)&Xs[(rb + r) * 128 + k];
            acc[r][0] = fmaf(x.x, w0.x, acc[r][0]); acc[r][0] = fmaf(x.y, w1.x, acc[r][0]);
            acc[r][0] = fmaf(x.z, w2.x, acc[r][0]); acc[r][0] = fmaf(x.w, w3.x, acc[r][0]);
            acc[r][1] = fmaf(x.x, w0.y, acc[r][1]); acc[r][1] = fmaf(x.y, w1.y, acc[r][1]);
            acc[r][1] = fmaf(x.z, w2.y, acc[r][1]); acc[r][1] = fmaf(x.w, w3.y, acc[r][1]);
            acc[r][2] = fmaf(x.x, w0.z, acc[r][2]); acc[r][2] = fmaf(x.y, w1.z, acc[r][2]);
            acc[r][2] = fmaf(x.z, w2.z, acc[r][2]); acc[r][2] = fmaf(x.w, w3.z, acc[r][2]);
            acc[r][3] = fmaf(x.x, w0.w, acc[r][3]); acc[r][3] = fmaf(x.y, w1.w, acc[r][3]);
            acc[r][3] = fmaf(x.z, w2.w, acc[r][3]); acc[r][3] = fmaf(x.w, w3.w, acc[r][3]);
          }
        }
        float4 btv = *(const float4*)(A.bt + c4);
        float hn[2][4];
#pragma unroll
        for (int r = 0; r < 2; ++r) {
          size_t row = r0 + rb + r;
          float4 gt = *(const float4*)(A.g + row * 384 + 256 + c4);
          float4 hv = *(const float4*)(hin + row * 128 + c4);
          float4 zv = *(const float4*)(A.zp + row * 128 + c4);
          hn[r][0] = hv.x + zv.x * (tanhf(acc[r][0] + gt.x + btv.x) - hv.x);
          hn[r][1] = hv.y + zv.y * (tanhf(acc[r][1] + gt.y + btv.y) - hv.y);
          hn[r][2] = hv.z + zv.z * (tanhf(acc[r][2] + gt.z + btv.z) - hv.z);
          hn[r][3] = hv.w + zv.w * (tanhf(acc[r][3] + gt.w + btv.w) - hv.w);
          float4 o = {hn[r][0], hn[r][1], hn[r][2], hn[r][3]};
          *(float4*)(A.h + row * 128 + c4) = o;
        }
        if (step == 2) {
          __syncthreads();
#pragma unroll
          for (int r = 0; r < 2; ++r) {
            float4 o = {hn[r][0], hn[r][1], hn[r][2], hn[r][3]};
            *(float4*)&Xs[(rb + r) * 128 + c4] = o;
          }
          __syncthreads();
          const float* WeT = A.Wa1T + 16384;
          float acc2[2][4] = {};
#pragma unroll 4
          for (int k = 0; k < 128; k += 4) {
            const float* wk = WeT + (size_t)k * 128 + c4;
            float4 w0 = *(const float4*)(wk);
            float4 w1 = *(const float4*)(wk + 128);
            float4 w2 = *(const float4*)(wk + 256);
            float4 w3 = *(const float4*)(wk + 384);
#pragma unroll
            for (int r = 0; r < 2; ++r) {
              float4 x = *(const float4*)&Xs[(rb + r) * 128 + k];
              acc2[r][0] = fmaf(x.x, w0.x, acc2[r][0]); acc2[r][0] = fmaf(x.y, w1.x, acc2[r][0]);
              acc2[r][0] = fmaf(x.z, w2.x, acc2[r][0]); acc2[r][0] = fmaf(x.w, w3.x, acc2[r][0]);
              acc2[r][1] = fmaf(x.x, w0.y, acc2[r][1]); acc2[r][1] = fmaf(x.y, w1.y, acc2[r][1]);
              acc2[r][1] = fmaf(x.z, w2.y, acc2[r][1]); acc2[r][1] = fmaf(x.w, w3.y, acc2[r][1]);
              acc2[r][2] = fmaf(x.x, w0.z, acc2[r][2]); acc2[r][2] = fmaf(x.y, w1.z, acc2[r][2]);
              acc2[r][2] = fmaf(x.z, w2.z, acc2[r][2]); acc2[r][2] = fmaf(x.w, w3.z, acc2[r][2]);
              acc2[r][3] = fmaf(x.x, w0.w, acc2[r][3]); acc2[r][3] = fmaf(x.y, w1.w, acc2[r][3]);
              acc2[r][3] = fmaf(x.z, w2.w, acc2[r][3]); acc2[r][3] = fmaf(x.w, w3.w, acc2[r][3]);
            }
          }
#pragma unroll
          for (int r = 0; r < 2; ++r) {
            float4 v = {acc2[r][0], acc2[r][1], acc2[r][2], acc2[r][3]};
            *(float4*)(A.kp + (size_t)(r0 + rb + r) * 128 + c4) = v;
          }
        }
        __syncthreads();
      } else {
        tile_gemm128(A.actions, A.Wa1T, nullptr, A.qp, (vb - 512) * 16, sm.b.Xs);
      }
    }
    gr.sync();
  }

  // ---- phase E: masked exp scores ----
  for (int vb = bid; vb < 512; vb += G) {
    int b = vb >> 5, qt = ((vb >> 4) & 1) * 32, kt = (vb & 15) * 32;
    const float* qsrc = A.qp + ((size_t)b * S2n + qt) * Hn;
    for (int f = t; f < 32 * 32; f += 256) {
      int q = f >> 5, g2 = f & 31;
      float4 v  = ((const float4*)qsrc)[f];
      float4 bb = ((const float4*)A.ba1)[g2];
      v.x += bb.x; v.y += bb.y; v.z += bb.z; v.w += bb.w;
      *(float4*)&sm.a.qs[q][4 * g2] = v;
    }
    const float* ksrc = A.kp + ((size_t)b * Sn + kt) * Hn;
    for (int f = t; f < 32 * 32; f += 256) {
      int k = f >> 5, g2 = f & 31;
      *(float4*)&sm.a.ks[k][4 * g2] = ((const float4*)ksrc)[f];
    }
    if (t < 128) sm.a.w2s[t] = A.Wa2[t];
    __syncthreads();
    const int q0 = (t & 15) * 2;
    const int k0 = (t >> 4) * 2;
    float acc[2][2] = {};
#pragma unroll 4
    for (int hh = 0; hh < 128; ++hh) {
      float w  = sm.a.w2s[hh];
      float kv0 = sm.a.ks[k0][hh], kv1 = sm.a.ks[k0 + 1][hh];
      float qv0 = sm.a.qs[q0][hh], qv1 = sm.a.qs[q0 + 1][hh];
      acc[0][0] = fmaf(fmaxf(qv0 + kv0, 0.f), w, acc[0][0]);
      acc[0][1] = fmaf(fmaxf(qv0 + kv1, 0.f), w, acc[0][1]);
      acc[1][0] = fmaf(fmaxf(qv1 + kv0, 0.f), w, acc[1][0]);
      acc[1][1] = fmaf(fmaxf(qv1 + kv1, 0.f), w, acc[1][1]);
    }
    float b2 = A.ba2[0];
#pragma unroll
    for (int i = 0; i < 2; ++i) {
      float amq = A.am[b * S2n + qt + q0 + i];
#pragma unroll
      for (int j = 0; j < 2; ++j) {
        float m = amq * A.sm[b * Sn + kt + k0 + j];
        float s = fmaxf(acc[i][j] + b2, 0.f);
        sm.a.es[q0 + i][k0 + j] = (m > 0.f) ? expf(s) : 0.f;
      }
    }
    __syncthreads();
    float* Eb = A.E + ((size_t)b * S2n + qt) * Sn + kt;
    for (int f = t; f < 32 * 32; f += 256) {
      int q = f >> 5, kin = f & 31;
      Eb[(size_t)q * Sn + kin] = sm.a.es[q][kin];
    }
    __syncthreads();
  }
  gr.sync();

  // ---- phase FG: attn weighted sum + adv ----
  for (int vb = bid; vb < 512; vb += G) {
    int b = vb >> 5;
    int half = t >> 7, tloc = t & 127;
    int q = (vb & 31) * 2 + half;
    size_t rowq = (size_t)b * S2n + q;
    const float* Erow = A.E + rowq * Sn;
    for (int i = tloc; i < Sn; i += 128) sm.fg.Es[half][i] = Erow[i];
    __syncthreads();
    float part = sm.fg.Es[half][tloc] + sm.fg.Es[half][tloc + 128] +
                 sm.fg.Es[half][tloc + 256] + sm.fg.Es[half][tloc + 384];
    part = wave_reduce_sum(part);
    if (lane == 0) sm.fg.red[wv] = part;
    __syncthreads();
    float scale = 1.f / fmaxf(sm.fg.red[half * 2] + sm.fg.red[half * 2 + 1], 2e-15f);
    const float* ob = A.h + (size_t)b * Sn * Hn + tloc;
    float acc = 0.f;
#pragma unroll 8
    for (int k = 0; k < Sn; ++k)
      acc = fmaf(sm.fg.Es[half][k], ob[(size_t)k * Hn], acc);
    float sfv = acc * scale;
    A.sfb[rowq * Hn + tloc] = sfv;
    sm.fg.sfs[half][tloc]  = sfv;
    sm.fg.acts[half][tloc] = A.actions[rowq * Hn + tloc];
    __syncthreads();
    for (int l = 0; l < Ln; ++l) {
      const float* wr = A.weight + ((size_t)l * Hn + tloc) * Hn;
      float tmp = 0.f;
#pragma unroll 4
      for (int k = 0; k < Hn; k += 4) {
        float4 wvv = *(const float4*)(wr + k);
        tmp = fmaf(wvv.x, sm.fg.sfs[half][k],     tmp);
        tmp = fmaf(wvv.y, sm.fg.sfs[half][k + 1], tmp);
        tmp = fmaf(wvv.z, sm.fg.sfs[half][k + 2], tmp);
        tmp = fmaf(wvv.w, sm.fg.sfs[half][k + 3], tmp);
      }
      float pa = sm.fg.acts[half][tloc] * tmp;
      pa = wave_reduce_sum(pa);
      if (lane == 0) sm.fg.redl[wv] = pa;
      __syncthreads();
      float tot = sm.fg.redl[half * 2] + sm.fg.redl[half * 2 + 1];
      if (tloc == 0) A.adv[rowq * Ln + l] = tot + A.bias[l];
      __syncthreads();
    }
  }
  gr.sync();

  // ---- phase H: final ----
  for (int vb = bid; vb < 16; vb += G) {
    int b = vb;
    float num = 0.f;
    for (int i = 0; i < S2n; ++i) num += A.am[b * S2n + i];
    float pv = 0.f;
    if (t < Hn) {
      float s = 0.f;
      const float* sb = A.sfb + (size_t)b * S2n * Hn + t;
      for (int q = 0; q < S2n; ++q) s += sb[(size_t)q * Hn];
      pv = A.Wv[t] * (s / num);
    }
    pv = wave_reduce_sum(pv);
    if (lane == 0) sm.red4[wv] = pv;
    __syncthreads();
    float val = sm.red4[0] + sm.red4[1] + sm.red4[2] + sm.red4[3] + A.bv[0];
    __syncthreads();
    const float* advb = A.adv + (size_t)b * S2n * Ln;
    float pa = (t < S2n * Ln) ? advb[t] : 0.f;
    pa = wave_reduce_sum(pa);
    if (lane == 0) sm.red4[wv] = pa;
    __syncthreads();
    float mean = (sm.red4[0] + sm.red4[1] + sm.red4[2] + sm.red4[3]) /
                 (float)(S2n * Ln);
    for (int i = t; i < S2n * Ln; i += 256)
      A.outq[(size_t)b * S2n * Ln + i] = val + advb[i] - mean;
    __syncthreads();
  }
}

// ================= fallback path (R14 kernels, verbatim) =================

__global__ __launch_bounds__(256) void prep1(
    const float* __restrict__ adj, float* __restrict__ deg,
    unsigned short* __restrict__ idx, int* __restrict__ cnts,
    const float* __restrict__ Wt, const float* __restrict__ Wa1,
    float* __restrict__ WtRT, float* __restrict__ Wa1T)
{
  __shared__ float t[32][33];
  int bid = blockIdx.x;
  if (bid < 2048) {
    int wid = TID >> 6, lane = TID & 63;
    int row = bid * 4 + wid;
    const float* ar = adj + (size_t)row * Sn;
    unsigned short* out = idx + (size_t)row * NNZ_CAP;
    int base = 0;
    for (int j0 = 0; j0 < Sn; j0 += 64) {
      float av = ar[j0 + lane];
      unsigned long long mask = __ballot(av != 0.f);
      int pos = __popcll(mask & ((1ull << lane) - 1ull));
      if (av != 0.f) out[base + pos] = (unsigned short)(j0 + lane);
      base += __popcll(mask);
    }
    if (lane == 0) { cnts[row] = base; deg[row] = (float)base; }
    return;
  }
  int flat = bid - 2048;
  const float* src; float* dst; int k0, n0, woff;
  if (flat < 16) { src = Wt;  dst = WtRT; k0 = (flat & 3) * 32; n0 = (flat >> 2) * 32; woff = 128; }
  else { int f2 = flat - 16; src = Wa1; dst = Wa1T; k0 = (f2 & 7) * 32; n0 = (f2 >> 3) * 32; woff = 0; }
  int tx = TID & 31, ty = TID >> 5;
#pragma unroll
  for (int i = 0; i < 32; i += 8)
    t[ty + i][tx] = src[(size_t)(n0 + ty + i) * 256 + woff + k0 + tx];
  __syncthreads();
#pragma unroll
  for (int i = 0; i < 32; i += 8)
    dst[(size_t)(k0 + ty + i) * 128 + n0 + tx] = t[tx][ty + i];
}

__global__ __launch_bounds__(128) void combine_pack(
    const float* __restrict__ Wn, const float* __restrict__ Wu,
    const float* __restrict__ Wr, const float* __restrict__ Wt,
    const float* __restrict__ bn, short* __restrict__ Bp,
    float* __restrict__ cu, float* __restrict__ cr, float* __restrict__ ct)
{
  int n = blockIdx.x, mat = blockIdx.y;
  const float* W = (mat == 0) ? Wu : (mat == 1) ? Wr : Wt;
  float* cv = (mat == 0) ? cu : (mat == 1) ? cr : ct;
  __shared__ float Ws[128], bns[128];
  __shared__ float red[2];
  int k = TID;
  Ws[k]  = W[(size_t)n * 256 + k];
  bns[k] = bn[k];
  __syncthreads();
  float acc = 0.f;
#pragma unroll 4
  for (int c = 0; c < 128; ++c)
    acc = fmaf(Wn[(size_t)c * 128 + k], Ws[c], acc);
  if (mat < 2) acc += W[(size_t)n * 256 + 128 + k];
  int idx2 = ((mat * 8 + (n >> 4)) * 4 + (k >> 5)) * 512 +
             (((k & 31) >> 3) * 16 + (n & 15)) * 8 + (k & 7);
  Bp[idx2] = (short)f2bf(acc);
  float pv = bns[k] * Ws[k];
  pv = wave_reduce_sum(pv);
  if ((k & 63) == 0) red[k >> 6] = pv;
  __syncthreads();
  if (k == 0) cv[n] = red[0] + red[1];
}

__global__ __launch_bounds__(256) void gemm_gf(
    const float* __restrict__ h, const short* __restrict__ Bp,
    const float* __restrict__ ctv, float* __restrict__ g)
{
  int w = TID >> 6, l = TID & 63;
  int r0 = blockIdx.x * 64 + w * 16;
  int mat = blockIdx.y;
  const float* abase = h + (size_t)(r0 + (l & 15)) * 128 + (l >> 4) * 8;
  bf16x8 a[4];
#pragma unroll
  for (int kc = 0; kc < 4; ++kc) {
    float4 f0 = *(const float4*)(abase + kc * 32);
    float4 f1 = *(const float4*)(abase + kc * 32 + 4);
    bf16x8 v;
    v[0] = (short)f2bf(f0.x); v[1] = (short)f2bf(f0.y);
    v[2] = (short)f2bf(f0.z); v[3] = (short)f2bf(f0.w);
    v[4] = (short)f2bf(f1.x); v[5] = (short)f2bf(f1.y);
    v[6] = (short)f2bf(f1.z); v[7] = (short)f2bf(f1.w);
    a[kc] = v;
  }
  f32x4 acc[8];
#pragma unroll
  for (int nt = 0; nt < 8; ++nt) acc[nt] = (f32x4){0.f, 0.f, 0.f, 0.f};
  const short* bbase = Bp + (size_t)(mat * 8) * 4 * 512 + l * 8;
#pragma unroll
  for (int nt = 0; nt < 8; ++nt)
#pragma unroll
    for (int kc = 0; kc < 4; ++kc) {
      bf16x8 b = *(const bf16x8*)(bbase + (nt * 4 + kc) * 512);
      acc[nt] = __builtin_amdgcn_mfma_f32_16x16x32_bf16(a[kc], b, acc[nt], 0, 0, 0);
    }
  int col0 = l & 15, rb2 = (l >> 4) * 4;
  float* gout = g + (size_t)(r0 + rb2) * 384 + mat * 128 + col0;
#pragma unroll
  for (int nt = 0; nt < 8; ++nt) {
    float cadd = (mat == 2) ? ctv[nt * 16 + col0] : 0.f;
#pragma unroll
    for (int r = 0; r < 4; ++r)
      gout[(size_t)r * 384 + nt * 16] = acc[nt][r] + cadd;
  }
}

__global__ __launch_bounds__(256) void adj_gate(
    const unsigned short* __restrict__ idx, const int* __restrict__ cnts,
    const float* __restrict__ g, const float* __restrict__ h,
    const float* __restrict__ cu, const float* __restrict__ cr,
    const float* __restrict__ bu, const float* __restrict__ br,
    float* __restrict__ z, float* __restrict__ rh)
{
  int wid = TID >> 6, lane = TID & 63;
  int b = blockIdx.y;
  int i = blockIdx.x * 4 + wid;
  size_t row = (size_t)b * Sn + i;
  int c = (lane < 32) ? 4 * lane : 128 + 4 * (lane - 32);
  const float* gb = g + (size_t)b * Sn * 384 + c;
  const unsigned short* ix = idx + row * NNZ_CAP;
  int cnt = cnts[row];
  float4 acc = {0.f, 0.f, 0.f, 0.f};
  int n = 0;
  for (; n + 4 <= cnt; n += 4) {
    ushort4 jj = *(const ushort4*)(ix + n);
    float4 x0 = *(const float4*)(gb + (size_t)jj.x * 384);
    float4 x1 = *(const float4*)(gb + (size_t)jj.y * 384);
    float4 x2 = *(const float4*)(gb + (size_t)jj.z * 384);
    float4 x3 = *(const float4*)(gb + (size_t)jj.w * 384);
    acc.x += (x0.x + x1.x) + (x2.x + x3.x);
    acc.y += (x0.y + x1.y) + (x2.y + x3.y);
    acc.z += (x0.z + x1.z) + (x2.z + x3.z);
    acc.w += (x0.w + x1.w) + (x2.w + x3.w);
  }
  for (; n < cnt; ++n) {
    int j = ix[n];
    float4 x = *(const float4*)(gb + (size_t)j * 384);
    acc.x += x.x; acc.y += x.y; acc.z += x.z; acc.w += x.w;
  }
  float d = (float)cnt;
  int cc = (lane < 32) ? 4 * lane : 4 * (lane - 32);
  const float* cvp = (lane < 32) ? cu : cr;
  const float* bvp = (lane < 32) ? bu : br;
  float4 cv = *(const float4*)(cvp + cc);
  float4 bv = *(const float4*)(bvp + cc);
  float4 sg;
  sg.x = sigm(acc.x + d * cv.x + bv.x);
  sg.y = sigm(acc.y + d * cv.y + bv.y);
  sg.z = sigm(acc.z + d * cv.z + bv.z);
  sg.w = sigm(acc.w + d * cv.w + bv.w);
  if (lane < 32) {
    *(float4*)(z + row * 128 + cc) = sg;
  } else {
    float4 hv = *(const float4*)(h + row * 128 + cc);
    sg.x *= hv.x; sg.y *= hv.y; sg.z *= hv.z; sg.w *= hv.w;
    *(float4*)(rh + row * 128 + cc) = sg;
  }
}

__global__ __launch_bounds__(256) void gemm_hh(
    const float* __restrict__ rh, const float* __restrict__ g,
    const float* __restrict__ WtRT, const float* __restrict__ bt,
    const float* __restrict__ z, const float* __restrict__ h_in,
    float* __restrict__ h_out,
    const float* __restrict__ WeT, float* __restrict__ e_out)
{
  __shared__ float Xs[16 * 128];
  int r0 = blockIdx.x * 16;
  const float* xsrc = rh + (size_t)r0 * 128;
  for (int i = TID; i < 512; i += 256)
    ((float4*)Xs)[i] = ((const float4*)xsrc)[i];
  __syncthreads();
  int c4 = (TID & 31) * 4;
  int rb = (TID >> 5) * 2;
  float acc[2][4] = {};
#pragma unroll 4
  for (int k = 0; k < 128; k += 4) {
    const float* wk = WtRT + (size_t)k * 128 + c4;
    float4 w0 = *(const float4*)(wk);
    float4 w1 = *(const float4*)(wk + 128);
    float4 w2 = *(const float4*)(wk + 256);
    float4 w3 = *(const float4*)(wk + 384);
#pragma unroll
    for (int r = 0; r < 2; ++r) {
      float4 x = *(const float4*)&Xs[(rb + r) * 128 + k];
      acc[r][0] = fmaf(x.x, w0.x, acc[r][0]); acc[r][0] = fmaf(x.y, w1.x, acc[r][0]);
      acc[r][0] = fmaf(x.z, w2.x, acc[r][0]); acc[r][0] = fmaf(x.w, w3.x, acc[r][0]);
      acc[r][1] = fmaf(x.x, w0.y, acc[r][1]); acc[r][1] = fmaf(x.y, w1.y, acc[r][1]);
      acc[r][1] = fmaf(x.z, w2.y, acc[r][1]); acc[r][1] = fmaf(x.w, w3.y, acc[r][1]);
      acc[r][2] = fmaf(x.x, w0.z, acc[r][2]); acc[r][2] = fmaf(x.y, w1.z, acc[r][2]);
      acc[r][2] = fmaf(x.z, w2.z, acc[r][2]); acc[r][2] = fmaf(x.w, w3.z, acc[r][2]);
      acc[r][3] = fmaf(x.x, w0.w, acc[r][3]); acc[r][3] = fmaf(x.y, w1.w, acc[r][3]);
      acc[r][3] = fmaf(x.z, w2.w, acc[r][3]); acc[r][3] = fmaf(x.w, w3.w, acc[r][3]);
    }
  }
  float4 btv = *(const float4*)(bt + c4);
  float hn[2][4];
#pragma unroll
  for (int r = 0; r < 2; ++r) {
    size_t row = r0 + rb + r;
    float4 gt = *(const float4*)(g + row * 384 + 256 + c4);
    float4 hv = *(const float4*)(h_in + row * 128 + c4);
    float4 zv = *(const float4*)(z + row * 128 + c4);
    hn[r][0] = hv.x + zv.x * (tanhf(acc[r][0] + gt.x + btv.x) - hv.x);
    hn[r][1] = hv.y + zv.y * (tanhf(acc[r][1] + gt.y + btv.y) - hv.y);
    hn[r][2] = hv.z + zv.z * (tanhf(acc[r][2] + gt.z + btv.z) - hv.z);
    hn[r][3] = hv.w + zv.w * (tanhf(acc[r][3] + gt.w + btv.w) - hv.w);
    float4 o = {hn[r][0], hn[r][1], hn[r][2], hn[r][3]};
    *(float4*)(h_out + row * 128 + c4) = o;
  }
  if (WeT) {
    __syncthreads();
#pragma unroll
    for (int r = 0; r < 2; ++r) {
      float4 o = {hn[r][0], hn[r][1], hn[r][2], hn[r][3]};
      *(float4*)&Xs[(rb + r) * 128 + c4] = o;
    }
    __syncthreads();
    float acc2[2][4] = {};
#pragma unroll 4
    for (int k = 0; k < 128; k += 4) {
      const float* wk = WeT + (size_t)k * 128 + c4;
      float4 w0 = *(const float4*)(wk);
      float4 w1 = *(const float4*)(wk + 128);
      float4 w2 = *(const float4*)(wk + 256);
      float4 w3 = *(const float4*)(wk + 384);
#pragma unroll
      for (int r = 0; r < 2; ++r) {
        float4 x = *(const float4*)&Xs[(rb + r) * 128 + k];
        acc2[r][0] = fmaf(x.x, w0.x, acc2[r][0]); acc2[r][0] = fmaf(x.y, w1.x, acc2[r][0]);
        acc2[r][0] = fmaf(x.z, w2.x, acc2[r][0]); acc2[r][0] = fmaf(x.w, w3.x, acc2[r][0]);
        acc2[r][1] = fmaf(x.x, w0.y, acc2[r][1]); acc2[r][1] = fmaf(x.y, w1.y, acc2[r][1]);
        acc2[r][1] = fmaf(x.z, w2.y, acc2[r][1]); acc2[r][1] = fmaf(x.w, w3.y, acc2[r][1]);
        acc2[r][2] = fmaf(x.x, w0.z, acc2[r][2]); acc2[r][2] = fmaf(x.y, w1.z, acc2[r][2]);
        acc2[r][2] = fmaf(x.z, w2.z, acc2[r][2]); acc2[r][2] = fmaf(x.w, w3.z, acc2[r][2]);
        acc2[r][3] = fmaf(x.x, w0.w, acc2[r][3]); acc2[r][3] = fmaf(x.y, w1.w, acc2[r][3]);
        acc2[r][3] = fmaf(x.z, w2.w, acc2[r][3]); acc2[r][3] = fmaf(x.w, w3.w, acc2[r][3]);
      }
    }
#pragma unroll
    for (int r = 0; r < 2; ++r) {
      float4 v = {acc2[r][0], acc2[r][1], acc2[r][2], acc2[r][3]};
      *(float4*)(e_out + (size_t)(r0 + rb + r) * 128 + c4) = v;
    }
  }
}

__global__ __launch_bounds__(256) void gemm_wt(
    const float* __restrict__ X, const float* __restrict__ WT,
    const float* __restrict__ bias, float* __restrict__ Y,
    int M, int K)
{
  extern __shared__ float Xs[];
  int r0 = blockIdx.x * 16;
  const float* xsrc = X + (size_t)r0 * K;
  int tot4 = (16 * K) >> 2;
  for (int i = TID; i < tot4; i += 256)
    ((float4*)Xs)[i] = ((const float4*)xsrc)[i];
  __syncthreads();
  int c4 = (TID & 31) * 4;
  int rb = (TID >> 5) * 2;
  float acc[2][4] = {};
#pragma unroll 4
  for (int k = 0; k < K; k += 4) {
    const float* wk = WT + (size_t)k * 128 + c4;
    float4 w0 = *(const float4*)(wk);
    float4 w1 = *(const float4*)(wk + 128);
    float4 w2 = *(const float4*)(wk + 256);
    float4 w3 = *(const float4*)(wk + 384);
#pragma unroll
    for (int r = 0; r < 2; ++r) {
      float4 x = *(const float4*)&Xs[(rb + r) * K + k];
      acc[r][0] = fmaf(x.x, w0.x, acc[r][0]); acc[r][0] = fmaf(x.y, w1.x, acc[r][0]);
      acc[r][0] = fmaf(x.z, w2.x, acc[r][0]); acc[r][0] = fmaf(x.w, w3.x, acc[r][0]);
      acc[r][1] = fmaf(x.x, w0.y, acc[r][1]); acc[r][1] = fmaf(x.y, w1.y, acc[r][1]);
      acc[r][1] = fmaf(x.z, w2.y, acc[r][1]); acc[r][1] = fmaf(x.w, w3.y, acc[r][1]);
      acc[r][2] = fmaf(x.x, w0.z, acc[r][2]); acc[r][2] = fmaf(x.y, w1.z, acc[r][2]);
      acc[r][2] = fmaf(x.z, w2.z, acc[r][2]); acc[r][2] = fmaf(x.w, w3.z, acc[r][2]);
      acc[r][3] = fmaf(x.x, w0.w, acc[r][3]); acc[r][3] = fmaf(x.y, w1.w, acc[r][3]);
      acc[r][3] = fmaf(x.z, w2.w, acc[r][3]); acc[r][3] = fmaf(x.w, w3.w, acc[r][3]);
    }
  }
  float4 bv = {0.f, 0.f, 0.f, 0.f};
  if (bias) bv = *(const float4*)(bias + c4);
#pragma unroll
  for (int r = 0; r < 2; ++r) {
    float4 v = {acc[r][0] + bv.x, acc[r][1] + bv.y,
                acc[r][2] + bv.z, acc[r][3] + bv.w};
    *(float4*)(Y + (size_t)(r0 + rb + r) * 128 + c4) = v;
  }
}

__global__ __launch_bounds__(256) void scores_exp_v3(
    const float* __restrict__ qp, const float* __restrict__ kp,
    const float* __restrict__ ba1, const float* __restrict__ Wa2,
    const float* __restrict__ ba2, const float* __restrict__ am,
    const float* __restrict__ smk, float* __restrict__ E)
{
  constexpr int KT = 32, QT = 32;
  __shared__ float qs[QT][132];
  __shared__ float ks[KT][132];
  __shared__ float w2s[128];
  __shared__ float es[QT][33];
  int b = blockIdx.z, kt = blockIdx.x * KT, qt = blockIdx.y * QT;
  const float* qsrc = qp + ((size_t)b * S2n + qt) * Hn;
  for (int f = TID; f < QT * 32; f += 256) {
    int q = f >> 5, g = f & 31;
    float4 v  = ((const float4*)qsrc)[f];
    float4 bb = ((const float4*)ba1)[g];
    v.x += bb.x; v.y += bb.y; v.z += bb.z; v.w += bb.w;
    *(float4*)&qs[q][4 * g] = v;
  }
  const float* ksrc = kp + ((size_t)b * Sn + kt) * Hn;
  for (int f = TID; f < KT * 32; f += 256) {
    int k = f >> 5, g = f & 31;
    *(float4*)&ks[k][4 * g] = ((const float4*)ksrc)[f];
  }
  if (TID < 128) w2s[TID] = Wa2[TID];
  __syncthreads();
  const int q0 = (TID & 15) * 2;
  const int k0 = (TID >> 4) * 2;
  float acc[2][2] = {};
#pragma unroll 4
  for (int h = 0; h < 128; ++h) {
    float w  = w2s[h];
    float kv0 = ks[k0][h], kv1 = ks[k0 + 1][h];
    float qv0 = qs[q0][h], qv1 = qs[q0 + 1][h];
    acc[0][0] = fmaf(fmaxf(qv0 + kv0, 0.f), w, acc[0][0]);
    acc[0][1] = fmaf(fmaxf(qv0 + kv1, 0.f), w, acc[0][1]);
    acc[1][0] = fmaf(fmaxf(qv1 + kv0, 0.f), w, acc[1][0]);
    acc[1][1] = fmaf(fmaxf(qv1 + kv1, 0.f), w, acc[1][1]);
  }
  float b2 = ba2[0];
#pragma unroll
  for (int i = 0; i < 2; ++i) {
    float amq = am[b * S2n + qt + q0 + i];
#pragma unroll
    for (int j = 0; j < 2; ++j) {
      float m = amq * smk[b * Sn + kt + k0 + j];
      float s = fmaxf(acc[i][j] + b2, 0.f);
      es[q0 + i][k0 + j] = (m > 0.f) ? expf(s) : 0.f;
    }
  }
  __syncthreads();
  float* Eb = E + ((size_t)b * S2n + qt) * Sn + kt;
  for (int f = TID; f < QT * KT; f += 256) {
    int q = f >> 5, kin = f & 31;
    Eb[(size_t)q * Sn + kin] = es[q][kin];
  }
}

__global__ __launch_bounds__(128) void attn_sf(
    const float* __restrict__ E, const float* __restrict__ out,
    float* __restrict__ sf)
{
  __shared__ float Es[512];
  __shared__ float red[2];
  int b = blockIdx.y, q = blockIdx.x, t = TID;
  const float* Erow = E + ((size_t)b * S2n + q) * Sn;
  for (int i = t; i < Sn; i += 128) Es[i] = Erow[i];
  __syncthreads();
  float part = Es[t] + Es[t + 128] + Es[t + 256] + Es[t + 384];
  part = wave_reduce_sum(part);
  if ((t & 63) == 0) red[t >> 6] = part;
  __syncthreads();
  float scale = 1.f / fmaxf(red[0] + red[1], 2e-15f);
  const float* ob = out + (size_t)b * Sn * Hn + t;
  float acc = 0.f;
#pragma unroll 8
  for (int k = 0; k < Sn; ++k) acc = fmaf(Es[k], ob[(size_t)k * Hn], acc);
  sf[((size_t)b * S2n + q) * Hn + t] = acc * scale;
}

__global__ __launch_bounds__(128) void adv_kernel(
    const float* __restrict__ actions, const float* __restrict__ sf,
    const float* __restrict__ weight, const float* __restrict__ bias,
    float* __restrict__ adv)
{
  __shared__ float acts[128], sfs[128];
  __shared__ float red[2];
  int b = blockIdx.y, s = blockIdx.x, t = TID;
  size_t row = (size_t)b * S2n + s;
  acts[t] = actions[row * Hn + t];
  sfs[t]  = sf[row * Hn + t];
  __syncthreads();
  for (int l = 0; l < Ln; ++l) {
    const float* wr = weight + ((size_t)l * Hn + t) * Hn;
    float tmp = 0.f;
#pragma unroll 4
    for (int k = 0; k < Hn; k += 4) {
      float4 wv = *(const float4*)(wr + k);
      tmp = fmaf(wv.x, sfs[k],     tmp);
      tmp = fmaf(wv.y, sfs[k + 1], tmp);
      tmp = fmaf(wv.z, sfs[k + 2], tmp);
      tmp = fmaf(wv.w, sfs[k + 3], tmp);
    }
    float pa  = acts[t] * tmp;
    float tot = block_reduce_sum(pa, red);
    if (t == 0) adv[row * Ln + l] = tot + bias[l];
  }
}

__global__ __launch_bounds__(256) void final2_kernel(
    const float* __restrict__ sf, const float* __restrict__ am,
    const float* __restrict__ Wv, const float* __restrict__ bv,
    const float* __restrict__ adv, float* __restrict__ outq)
{
  __shared__ float red[4];
  int b = blockIdx.x, t = TID;
  float num = 0.f;
  for (int i = 0; i < S2n; ++i) num += am[b * S2n + i];
  float pv = 0.f;
  if (t < Hn) {
    float s = 0.f;
    const float* sb = sf + (size_t)b * S2n * Hn + t;
    for (int q = 0; q < S2n; ++q) s += sb[(size_t)q * Hn];
    pv = Wv[t] * (s / num);
  }
  float val = block_reduce_sum(pv, red) + bv[0];
  const float* advb = adv + (size_t)b * S2n * Ln;
  float pa   = (t < S2n * Ln) ? advb[t] : 0.f;
  float mean = block_reduce_sum(pa, red) / (float)(S2n * Ln);
  for (int i = t; i < S2n * Ln; i += 256)
    outq[(size_t)b * S2n * Ln + i] = val + advb[i] - mean;
}

extern "C" void kernel_launch(void* const* d_in, const int* in_sizes, int n_in,
                              void* d_out, int out_size, void* d_ws, size_t ws_size,
                              hipStream_t stream)
{
  float* ws = (float*)d_ws;
  MegaArgs A;
  A.states = (const float*)d_in[0];
  A.sm     = (const float*)d_in[1];
  A.actions= (const float*)d_in[2];
  A.am     = (const float*)d_in[3];
  A.adj    = (const float*)d_in[4];
  A.Wn  = (const float*)d_in[5];  A.bn  = (const float*)d_in[6];
  A.Wu  = (const float*)d_in[7];  A.bu  = (const float*)d_in[8];
  A.Wr  = (const float*)d_in[9];  A.br  = (const float*)d_in[10];
  A.Wt  = (const float*)d_in[11]; A.bt  = (const float*)d_in[12];
  A.Wa1 = (const float*)d_in[13]; A.ba1 = (const float*)d_in[14];
  A.Wa2 = (const float*)d_in[15]; A.ba2 = (const float*)d_in[16];
  A.Wv  = (const float*)d_in[17]; A.bv  = (const float*)d_in[18];
  A.weight = (const float*)d_in[19];
  A.bias   = (const float*)d_in[20];

  A.h    = ws;
  A.g    = ws + (1 << 20);
  A.zp   = ws + 4 * (1 << 20);
  A.rh   = ws + 5 * (1 << 20);
  A.kp   = ws + 6 * (1 << 20);
  A.qp   = ws + 7 * (1 << 20);
  A.E    = ws + 8 * (1 << 20);
  A.sfb  = ws + 9 * (1 << 20);
  A.adv  = A.sfb + 262144;
  float* aux = ws + 10 * (1 << 20);
  A.WtRT = aux;
  A.Wa1T = aux + 16384;
  A.cu   = aux + 16384 + 32768;
  A.cr   = A.cu + 128;
  A.ct   = A.cr + 128;
  A.Bp   = (short*)(ws + 12 * (1 << 20));
  A.idx  = (unsigned short*)(ws + 13 * (1 << 20));
  A.cnts = (int*)(ws + 14 * (1 << 20));
  A.outq = (float*)d_out;

  // Deterministic host-side feasibility check for cooperative launch.
  int maxB = 0;
  hipError_t qerr = hipOccupancyMaxActiveBlocksPerMultiprocessor(
      &maxB, (const void*)mega, 256, 0);
  int grid = 0;
  if (qerr == hipSuccess && maxB > 0) {
    grid = maxB * 256;             // 256 CUs on MI355X
    if (grid > 512) grid = 512;
  }

  if (grid >= 64) {
    void* params[] = {(void*)&A};
    hipLaunchCooperativeKernel((const void*)mega, dim3(grid), dim3(256),
                               params, 0, stream);
    return;
  }

  // ---- fallback: proven R14 multi-kernel path ----
  float* deg = ws + 11 * (1 << 20);
  const int M = Bn * Sn;
  const int lds128 = 16 * 128 * 4;
  prep1<<<2048 + 48, 256, 0, stream>>>(A.adj, deg, A.idx, A.cnts, A.Wt, A.Wa1,
                                       A.WtRT, A.Wa1T);
  combine_pack<<<dim3(128, 3), 128, 0, stream>>>(A.Wn, A.Wu, A.Wr, A.Wt, A.bn,
                                                 A.Bp, A.cu, A.cr, A.ct);
  for (int step = 0; step < 3; ++step) {
    const float* hin = (step == 0) ? A.states : A.h;
    gemm_gf<<<dim3(M / 64, 3), 256, 0, stream>>>(hin, A.Bp, A.ct, A.g);
    adj_gate<<<dim3(Sn / 4, Bn), 256, 0, stream>>>(A.idx, A.cnts, A.g, hin,
                                                   A.cu, A.cr, A.bu, A.br,
                                                   A.zp, A.rh);
    gemm_hh<<<M / 16, 256, 0, stream>>>(A.rh, A.g, A.WtRT, A.bt, A.zp, hin,
                                        A.h,
                                        step == 2 ? A.Wa1T + 16384 : nullptr,
                                        A.kp);
  }
  gemm_wt<<<(Bn * S2n) / 16, 256, lds128, stream>>>(A.actions, A.Wa1T, nullptr,
                                                    A.qp, Bn * S2n, 128);
  scores_exp_v3<<<dim3(Sn / 32, 2, Bn), 256, 0, stream>>>(
      A.qp, A.kp, A.ba1, A.Wa2, A.ba2, A.am, A.sm, A.E);
  attn_sf<<<dim3(S2n, Bn), 128, 0, stream>>>(A.E, A.h, A.sfb);
  adv_kernel<<<dim3(S2n, Bn), 128, 0, stream>>>(A.actions, A.sfb, A.weight,
                                                A.bias, A.adv);
  final2_kernel<<<Bn, 256, 0, stream>>>(A.sfb, A.am, A.Wv, A.bv, A.adv,
                                        A.outq);
}

// Round 18
// 237.927 us; speedup vs baseline: 3.0181x; 3.0181x over previous
//
#include <hip/hip_runtime.h>
#include <math.h>

constexpr int Bn  = 16;
constexpr int Sn  = 512;
constexpr int S2n = 64;
constexpr int Hn  = 128;
constexpr int Ln  = 3;
constexpr int NNZ_CAP = 128;

#define TID ((int)threadIdx.x)

typedef __attribute__((ext_vector_type(8))) short bf16x8;
typedef __attribute__((ext_vector_type(4))) float f32x4;

__device__ inline float wave_reduce_sum(float v) {
#pragma unroll
  for (int off = 32; off > 0; off >>= 1) v += __shfl_xor(v, off, 64);
  return v;
}

__device__ inline float block_reduce_sum(float v, float* red) {
  v = wave_reduce_sum(v);
  int w  = TID >> 6;
  int nw = (int)blockDim.x >> 6;
  if ((TID & 63) == 0) red[w] = v;
  __syncthreads();
  float s = 0.f;
  for (int i = 0; i < nw; ++i) s += red[i];
  __syncthreads();
  return s;
}

__device__ inline float sigm(float x) { return 1.f / (1.f + expf(-x)); }

__device__ inline unsigned short f2bf(float f) {
  unsigned int u = __float_as_uint(f);
  u = (u + 0x7fffu + ((u >> 16) & 1u)) >> 16;
  return (unsigned short)u;
}

// prep1: bid<2048 -> compact adjacency rows to index lists (binary adj).
// bid>=2048 -> 32x32 transpose tiles for WtRT (16) and Wa1T (32).
__global__ __launch_bounds__(256) void prep1(
    const float* __restrict__ adj,
    unsigned short* __restrict__ idx, int* __restrict__ cnts,
    const float* __restrict__ Wt, const float* __restrict__ Wa1,
    float* __restrict__ WtRT, float* __restrict__ Wa1T)
{
  __shared__ float t[32][33];
  int bid = blockIdx.x;
  if (bid < 2048) {
    int wid = TID >> 6, lane = TID & 63;
    int row = bid * 4 + wid;
    const float* ar = adj + (size_t)row * Sn;
    unsigned short* out = idx + (size_t)row * NNZ_CAP;
    int base = 0;
    for (int j0 = 0; j0 < Sn; j0 += 64) {
      float av = ar[j0 + lane];
      unsigned long long mask = __ballot(av != 0.f);
      int pos = __popcll(mask & ((1ull << lane) - 1ull));
      if (av != 0.f) out[base + pos] = (unsigned short)(j0 + lane);
      base += __popcll(mask);
    }
    if (lane == 0) cnts[row] = base;
    return;
  }
  int flat = bid - 2048;
  const float* src; float* dst; int k0, n0, woff;
  if (flat < 16) { src = Wt;  dst = WtRT; k0 = (flat & 3) * 32; n0 = (flat >> 2) * 32; woff = 128; }
  else { int f2 = flat - 16; src = Wa1; dst = Wa1T; k0 = (f2 & 7) * 32; n0 = (f2 >> 3) * 32; woff = 0; }
  int tx = TID & 31, ty = TID >> 5;
#pragma unroll
  for (int i = 0; i < 32; i += 8)
    t[ty + i][tx] = src[(size_t)(n0 + ty + i) * 256 + woff + k0 + tx];
  __syncthreads();
#pragma unroll
  for (int i = 0; i < 32; i += 8)
    dst[(size_t)(k0 + ty + i) * 128 + n0 + tx] = t[tx][ty + i];
}

// Combined matrices packed to bf16 MFMA B-fragments; cvec[n] = bn . W[n,:128].
__global__ __launch_bounds__(128) void combine_pack(
    const float* __restrict__ Wn, const float* __restrict__ Wu,
    const float* __restrict__ Wr, const float* __restrict__ Wt,
    const float* __restrict__ bn, short* __restrict__ Bp,
    float* __restrict__ cu, float* __restrict__ cr, float* __restrict__ ct)
{
  int n = blockIdx.x, mat = blockIdx.y;
  const float* W = (mat == 0) ? Wu : (mat == 1) ? Wr : Wt;
  float* cv = (mat == 0) ? cu : (mat == 1) ? cr : ct;
  __shared__ float Ws[128], bns[128];
  __shared__ float red[2];
  int k = TID;
  Ws[k]  = W[(size_t)n * 256 + k];
  bns[k] = bn[k];
  __syncthreads();
  float acc = 0.f;
#pragma unroll 4
  for (int c = 0; c < 128; ++c)
    acc = fmaf(Wn[(size_t)c * 128 + k], Ws[c], acc);
  if (mat < 2) acc += W[(size_t)n * 256 + 128 + k];
  int idx2 = ((mat * 8 + (n >> 4)) * 4 + (k >> 5)) * 512 +
             (((k & 31) >> 3) * 16 + (n & 15)) * 8 + (k & 7);
  Bp[idx2] = (short)f2bf(acc);
  float pv = bns[k] * Ws[k];
  pv = wave_reduce_sum(pv);
  if ((k & 63) == 0) red[k >> 6] = pv;
  __syncthreads();
  if (k == 0) cv[n] = red[0] + red[1];
}

// MFMA bf16 gemm: g[row][mat*128+n] = h @ G_mat (+ct for mat 2).
__global__ __launch_bounds__(256) void gemm_gf(
    const float* __restrict__ h, const short* __restrict__ Bp,
    const float* __restrict__ ctv, float* __restrict__ g)
{
  int w = TID >> 6, l = TID & 63;
  int r0 = blockIdx.x * 64 + w * 16;
  int mat = blockIdx.y;
  const float* abase = h + (size_t)(r0 + (l & 15)) * 128 + (l >> 4) * 8;
  bf16x8 a[4];
#pragma unroll
  for (int kc = 0; kc < 4; ++kc) {
    float4 f0 = *(const float4*)(abase + kc * 32);
    float4 f1 = *(const float4*)(abase + kc * 32 + 4);
    bf16x8 v;
    v[0] = (short)f2bf(f0.x); v[1] = (short)f2bf(f0.y);
    v[2] = (short)f2bf(f0.z); v[3] = (short)f2bf(f0.w);
    v[4] = (short)f2bf(f1.x); v[5] = (short)f2bf(f1.y);
    v[6] = (short)f2bf(f1.z); v[7] = (short)f2bf(f1.w);
    a[kc] = v;
  }
  f32x4 acc[8];
#pragma unroll
  for (int nt = 0; nt < 8; ++nt) acc[nt] = (f32x4){0.f, 0.f, 0.f, 0.f};
  const short* bbase = Bp + (size_t)(mat * 8) * 4 * 512 + l * 8;
#pragma unroll
  for (int nt = 0; nt < 8; ++nt)
#pragma unroll
    for (int kc = 0; kc < 4; ++kc) {
      bf16x8 b = *(const bf16x8*)(bbase + (nt * 4 + kc) * 512);
      acc[nt] = __builtin_amdgcn_mfma_f32_16x16x32_bf16(a[kc], b, acc[nt], 0, 0, 0);
    }
  int col0 = l & 15, rb2 = (l >> 4) * 4;
  float* gout = g + (size_t)(r0 + rb2) * 384 + mat * 128 + col0;
#pragma unroll
  for (int nt = 0; nt < 8; ++nt) {
    float cadd = (mat == 2) ? ctv[nt * 16 + col0] : 0.f;
#pragma unroll
    for (int r = 0; r < 4; ++r)
      gout[(size_t)r * 384 + nt * 16] = acc[nt][r] + cadd;
  }
}

// Fused: idx-gather gates (z,rh -> LDS) + candidate gemm + combine.
// Flat grid: bid<512 -> tile (b=bid>>5, tile=bid&31); bid>=512 -> qp gemm.
// step==2: kp epilogue (WeT/e_out). step==0 launch adds 64 qp blocks.
__global__ __launch_bounds__(256) void adj_hh(
    const unsigned short* __restrict__ idx, const int* __restrict__ cnts,
    const float* __restrict__ g, const float* __restrict__ h_in,
    const float* __restrict__ cu, const float* __restrict__ cr,
    const float* __restrict__ bu, const float* __restrict__ br,
    const float* __restrict__ WtRT, const float* __restrict__ bt,
    float* __restrict__ h_out,
    const float* __restrict__ WeT, float* __restrict__ e_out,
    const float* __restrict__ qX, const float* __restrict__ qWT,
    float* __restrict__ qY)
{
  __shared__ float Xs[16 * 128];   // rh, then h_new for epilogue
  __shared__ float zs[16 * 128];   // z
  int bid = blockIdx.x;
  int t = TID, lane = t & 63, wv = t >> 6;

  if (bid >= 512) {
    // qp = actions @ Wa1TL (16-row tile gemm, LDS-staged)
    int r0 = (bid - 512) * 16;
    const float* xsrc = qX + (size_t)r0 * 128;
    for (int i = t; i < 512; i += 256)
      ((float4*)Xs)[i] = ((const float4*)xsrc)[i];
    __syncthreads();
    int c4 = (t & 31) * 4;
    int rb = (t >> 5) * 2;
    float acc[2][4] = {};
#pragma unroll 4
    for (int k = 0; k < 128; k += 4) {
      const float* wk = qWT + (size_t)k * 128 + c4;
      float4 w0 = *(const float4*)(wk);
      float4 w1 = *(const float4*)(wk + 128);
      float4 w2 = *(const float4*)(wk + 256);
      float4 w3 = *(const float4*)(wk + 384);
#pragma unroll
      for (int r = 0; r < 2; ++r) {
        float4 x = *(const float4*)&Xs[(rb + r) * 128 + k];
        acc[r][0] = fmaf(x.x, w0.x, acc[r][0]); acc[r][0] = fmaf(x.y, w1.x, acc[r][0]);
        acc[r][0] = fmaf(x.z, w2.x, acc[r][0]); acc[r][0] = fmaf(x.w, w3.x, acc[r][0]);
        acc[r][1] = fmaf(x.x, w0.y, acc[r][1]); acc[r][1] = fmaf(x.y, w1.y, acc[r][1]);
        acc[r][1] = fmaf(x.z, w2.y, acc[r][1]); acc[r][1] = fmaf(x.w, w3.y, acc[r][1]);
        acc[r][2] = fmaf(x.x, w0.z, acc[r][2]); acc[r][2] = fmaf(x.y, w1.z, acc[r][2]);
        acc[r][2] = fmaf(x.z, w2.z, acc[r][2]); acc[r][2] = fmaf(x.w, w3.z, acc[r][2]);
        acc[r][3] = fmaf(x.x, w0.w, acc[r][3]); acc[r][3] = fmaf(x.y, w1.w, acc[r][3]);
        acc[r][3] = fmaf(x.z, w2.w, acc[r][3]); acc[r][3] = fmaf(x.w, w3.w, acc[r][3]);
      }
    }
#pragma unroll
    for (int r = 0; r < 2; ++r) {
      float4 v = {acc[r][0], acc[r][1], acc[r][2], acc[r][3]};
      *(float4*)(qY + (size_t)(r0 + rb + r) * 128 + c4) = v;
    }
    return;
  }

  int b = bid >> 5, tile = bid & 31;

  // phase 1: gather gates into LDS (wave wv handles rows wv*4 .. wv*4+3)
  {
    int c  = (lane < 32) ? 4 * lane : 128 + 4 * (lane - 32);
    int cc = (lane < 32) ? 4 * lane : 4 * (lane - 32);
    const float* gb = g + (size_t)b * Sn * 384 + c;
    const float* cvp = (lane < 32) ? cu : cr;
    const float* bvp = (lane < 32) ? bu : br;
    float4 cv = *(const float4*)(cvp + cc);
    float4 bv = *(const float4*)(bvp + cc);
    for (int rr = 0; rr < 4; ++rr) {
      int li = wv * 4 + rr;
      size_t row = (size_t)b * Sn + tile * 16 + li;
      const unsigned short* ix = idx + row * NNZ_CAP;
      int cnt = cnts[row];
      float4 acc = {0.f, 0.f, 0.f, 0.f};
      int n = 0;
      for (; n + 4 <= cnt; n += 4) {
        ushort4 jj = *(const ushort4*)(ix + n);
        float4 x0 = *(const float4*)(gb + (size_t)jj.x * 384);
        float4 x1 = *(const float4*)(gb + (size_t)jj.y * 384);
        float4 x2 = *(const float4*)(gb + (size_t)jj.z * 384);
        float4 x3 = *(const float4*)(gb + (size_t)jj.w * 384);
        acc.x += (x0.x + x1.x) + (x2.x + x3.x);
        acc.y += (x0.y + x1.y) + (x2.y + x3.y);
        acc.z += (x0.z + x1.z) + (x2.z + x3.z);
        acc.w += (x0.w + x1.w) + (x2.w + x3.w);
      }
      for (; n < cnt; ++n) {
        int j = ix[n];
        float4 x = *(const float4*)(gb + (size_t)j * 384);
        acc.x += x.x; acc.y += x.y; acc.z += x.z; acc.w += x.w;
      }
      float d = (float)cnt;
      float4 sg;
      sg.x = sigm(acc.x + d * cv.x + bv.x);
      sg.y = sigm(acc.y + d * cv.y + bv.y);
      sg.z = sigm(acc.z + d * cv.z + bv.z);
      sg.w = sigm(acc.w + d * cv.w + bv.w);
      if (lane < 32) {
        *(float4*)&zs[li * 128 + cc] = sg;
      } else {
        float4 hv = *(const float4*)(h_in + row * 128 + cc);
        sg.x *= hv.x; sg.y *= hv.y; sg.z *= hv.z; sg.w *= hv.w;
        *(float4*)&Xs[li * 128 + cc] = sg;
      }
    }
  }
  __syncthreads();

  // phase 2: h_new = h + z*(tanh(rh@WtRT + g_t + bt) - h)
  int r0g = tile * 16;
  int c4 = (t & 31) * 4;
  int rb = (t >> 5) * 2;
  float acc[2][4] = {};
#pragma unroll 4
  for (int k = 0; k < 128; k += 4) {
    const float* wk = WtRT + (size_t)k * 128 + c4;
    float4 w0 = *(const float4*)(wk);
    float4 w1 = *(const float4*)(wk + 128);
    float4 w2 = *(const float4*)(wk + 256);
    float4 w3 = *(const float4*)(wk + 384);
#pragma unroll
    for (int r = 0; r < 2; ++r) {
      float4 x = *(const float4*)&Xs[(rb + r) * 128 + k];
      acc[r][0] = fmaf(x.x, w0.x, acc[r][0]); acc[r][0] = fmaf(x.y, w1.x, acc[r][0]);
      acc[r][0] = fmaf(x.z, w2.x, acc[r][0]); acc[r][0] = fmaf(x.w, w3.x, acc[r][0]);
      acc[r][1] = fmaf(x.x, w0.y, acc[r][1]); acc[r][1] = fmaf(x.y, w1.y, acc[r][1]);
      acc[r][1] = fmaf(x.z, w2.y, acc[r][1]); acc[r][1] = fmaf(x.w, w3.y, acc[r][1]);
      acc[r][2] = fmaf(x.x, w0.z, acc[r][2]); acc[r][2] = fmaf(x.y, w1.z, acc[r][2]);
      acc[r][2] = fmaf(x.z, w2.z, acc[r][2]); acc[r][2] = fmaf(x.w, w3.z, acc[r][2]);
      acc[r][3] = fmaf(x.x, w0.w, acc[r][3]); acc[r][3] = fmaf(x.y, w1.w, acc[r][3]);
      acc[r][3] = fmaf(x.z, w2.w, acc[r][3]); acc[r][3] = fmaf(x.w, w3.w, acc[r][3]);
    }
  }
  float4 btv = *(const float4*)(bt + c4);
  float hn[2][4];
#pragma unroll
  for (int r = 0; r < 2; ++r) {
    size_t row = (size_t)b * Sn + r0g + rb + r;
    float4 gt = *(const float4*)(g + row * 384 + 256 + c4);
    float4 hv = *(const float4*)(h_in + row * 128 + c4);
    float4 zv = *(const float4*)&zs[(rb + r) * 128 + c4];
    hn[r][0] = hv.x + zv.x * (tanhf(acc[r][0] + gt.x + btv.x) - hv.x);
    hn[r][1] = hv.y + zv.y * (tanhf(acc[r][1] + gt.y + btv.y) - hv.y);
    hn[r][2] = hv.z + zv.z * (tanhf(acc[r][2] + gt.z + btv.z) - hv.z);
    hn[r][3] = hv.w + zv.w * (tanhf(acc[r][3] + gt.w + btv.w) - hv.w);
    float4 o = {hn[r][0], hn[r][1], hn[r][2], hn[r][3]};
    *(float4*)(h_out + row * 128 + c4) = o;
  }

  if (WeT) {   // kp = h_new @ Wa1TR (row-local epilogue, last step only)
    __syncthreads();
#pragma unroll
    for (int r = 0; r < 2; ++r) {
      float4 o = {hn[r][0], hn[r][1], hn[r][2], hn[r][3]};
      *(float4*)&Xs[(rb + r) * 128 + c4] = o;
    }
    __syncthreads();
    float acc2[2][4] = {};
#pragma unroll 4
    for (int k = 0; k < 128; k += 4) {
      const float* wk = WeT + (size_t)k * 128 + c4;
      float4 w0 = *(const float4*)(wk);
      float4 w1 = *(const float4*)(wk + 128);
      float4 w2 = *(const float4*)(wk + 256);
      float4 w3 = *(const float4*)(wk + 384);
#pragma unroll
      for (int r = 0; r < 2; ++r) {
        float4 x = *(const float4*)&Xs[(rb + r) * 128 + k];
        acc2[r][0] = fmaf(x.x, w0.x, acc2[r][0]); acc2[r][0] = fmaf(x.y, w1.x, acc2[r][0]);
        acc2[r][0] = fmaf(x.z, w2.x, acc2[r][0]); acc2[r][0] = fmaf(x.w, w3.x, acc2[r][0]);
        acc2[r][1] = fmaf(x.x, w0.y, acc2[r][1]); acc2[r][1] = fmaf(x.y, w1.y, acc2[r][1]);
        acc2[r][1] = fmaf(x.z, w2.y, acc2[r][1]); acc2[r][1] = fmaf(x.w, w3.y, acc2[r][1]);
        acc2[r][2] = fmaf(x.x, w0.z, acc2[r][2]); acc2[r][2] = fmaf(x.y, w1.z, acc2[r][2]);
        acc2[r][2] = fmaf(x.z, w2.z, acc2[r][2]); acc2[r][2] = fmaf(x.w, w3.z, acc2[r][2]);
        acc2[r][3] = fmaf(x.x, w0.w, acc2[r][3]); acc2[r][3] = fmaf(x.y, w1.w, acc2[r][3]);
        acc2[r][3] = fmaf(x.z, w2.w, acc2[r][3]); acc2[r][3] = fmaf(x.w, w3.w, acc2[r][3]);
      }
    }
#pragma unroll
    for (int r = 0; r < 2; ++r) {
      float4 v = {acc2[r][0], acc2[r][1], acc2[r][2], acc2[r][3]};
      *(float4*)(e_out + ((size_t)b * Sn + r0g + rb + r) * 128 + c4) = v;
    }
  }
}

// E[b,q,k] = mask ? exp(relu(Wa2 . relu(qp[b,q]+kp[b,k]+ba1) + ba2)) : 0
__global__ __launch_bounds__(256) void scores_exp_v3(
    const float* __restrict__ qp, const float* __restrict__ kp,
    const float* __restrict__ ba1, const float* __restrict__ Wa2,
    const float* __restrict__ ba2, const float* __restrict__ am,
    const float* __restrict__ smk, float* __restrict__ E)
{
  constexpr int KT = 32, QT = 32;
  __shared__ float qs[QT][132];
  __shared__ float ks[KT][132];
  __shared__ float w2s[128];
  __shared__ float es[QT][33];
  int b = blockIdx.z, kt = blockIdx.x * KT, qt = blockIdx.y * QT;
  const float* qsrc = qp + ((size_t)b * S2n + qt) * Hn;
  for (int f = TID; f < QT * 32; f += 256) {
    int q = f >> 5, g = f & 31;
    float4 v  = ((const float4*)qsrc)[f];
    float4 bb = ((const float4*)ba1)[g];
    v.x += bb.x; v.y += bb.y; v.z += bb.z; v.w += bb.w;
    *(float4*)&qs[q][4 * g] = v;
  }
  const float* ksrc = kp + ((size_t)b * Sn + kt) * Hn;
  for (int f = TID; f < KT * 32; f += 256) {
    int k = f >> 5, g = f & 31;
    *(float4*)&ks[k][4 * g] = ((const float4*)ksrc)[f];
  }
  if (TID < 128) w2s[TID] = Wa2[TID];
  __syncthreads();
  const int q0 = (TID & 15) * 2;
  const int k0 = (TID >> 4) * 2;
  float acc[2][2] = {};
#pragma unroll 4
  for (int h = 0; h < 128; ++h) {
    float w  = w2s[h];
    float kv0 = ks[k0][h], kv1 = ks[k0 + 1][h];
    float qv0 = qs[q0][h], qv1 = qs[q0 + 1][h];
    acc[0][0] = fmaf(fmaxf(qv0 + kv0, 0.f), w, acc[0][0]);
    acc[0][1] = fmaf(fmaxf(qv0 + kv1, 0.f), w, acc[0][1]);
    acc[1][0] = fmaf(fmaxf(qv1 + kv0, 0.f), w, acc[1][0]);
    acc[1][1] = fmaf(fmaxf(qv1 + kv1, 0.f), w, acc[1][1]);
  }
  float b2 = ba2[0];
#pragma unroll
  for (int i = 0; i < 2; ++i) {
    float amq = am[b * S2n + qt + q0 + i];
#pragma unroll
    for (int j = 0; j < 2; ++j) {
      float m = amq * smk[b * Sn + kt + k0 + j];
      float s = fmaxf(acc[i][j] + b2, 0.f);
      es[q0 + i][k0 + j] = (m > 0.f) ? expf(s) : 0.f;
    }
  }
  __syncthreads();
  float* Eb = E + ((size_t)b * S2n + qt) * Sn + kt;
  for (int f = TID; f < QT * KT; f += 256) {
    int q = f >> 5, kin = f & 31;
    Eb[(size_t)q * Sn + kin] = es[q][kin];
  }
}

// Fused attn weighted sum + adv: block = (q-pair, b); 128 threads per q.
__global__ __launch_bounds__(256) void fused_fg(
    const float* __restrict__ E, const float* __restrict__ h,
    const float* __restrict__ actions, const float* __restrict__ weight,
    const float* __restrict__ bias, float* __restrict__ sf,
    float* __restrict__ adv)
{
  __shared__ float Es[2][512];
  __shared__ float red[4];
  __shared__ float sfs[2][128];
  __shared__ float acts[2][128];
  __shared__ float redl[4];
  int b = blockIdx.y;
  int t = TID, lane = t & 63, wv = t >> 6;
  int half = t >> 7, tloc = t & 127;
  int q = blockIdx.x * 2 + half;
  size_t rowq = (size_t)b * S2n + q;
  const float* Erow = E + rowq * Sn;
  for (int i = tloc; i < Sn; i += 128) Es[half][i] = Erow[i];
  __syncthreads();
  float part = Es[half][tloc] + Es[half][tloc + 128] +
               Es[half][tloc + 256] + Es[half][tloc + 384];
  part = wave_reduce_sum(part);
  if (lane == 0) red[wv] = part;
  __syncthreads();
  float scale = 1.f / fmaxf(red[half * 2] + red[half * 2 + 1], 2e-15f);
  const float* ob = h + (size_t)b * Sn * Hn + tloc;
  float acc = 0.f;
#pragma unroll 8
  for (int k = 0; k < Sn; ++k)
    acc = fmaf(Es[half][k], ob[(size_t)k * Hn], acc);
  float sfv = acc * scale;
  sf[rowq * Hn + tloc] = sfv;
  sfs[half][tloc]  = sfv;
  acts[half][tloc] = actions[rowq * Hn + tloc];
  __syncthreads();
  for (int l = 0; l < Ln; ++l) {
    const float* wr = weight + ((size_t)l * Hn + tloc) * Hn;
    float tmp = 0.f;
#pragma unroll 4
    for (int k = 0; k < Hn; k += 4) {
      float4 wv4 = *(const float4*)(wr + k);
      tmp = fmaf(wv4.x, sfs[half][k],     tmp);
      tmp = fmaf(wv4.y, sfs[half][k + 1], tmp);
      tmp = fmaf(wv4.z, sfs[half][k + 2], tmp);
      tmp = fmaf(wv4.w, sfs[half][k + 3], tmp);
    }
    float pa = acts[half][tloc] * tmp;
    pa = wave_reduce_sum(pa);
    if (lane == 0) redl[wv] = pa;
    __syncthreads();
    float tot = redl[half * 2] + redl[half * 2 + 1];
    if (tloc == 0) adv[rowq * Ln + l] = tot + bias[l];
    __syncthreads();
  }
}

// Fused: sem = mean_q sf ; val = Wv.sem+bv ; q = val + adv - mean(adv)
__global__ __launch_bounds__(256) void final2_kernel(
    const float* __restrict__ sf, const float* __restrict__ am,
    const float* __restrict__ Wv, const float* __restrict__ bv,
    const float* __restrict__ adv, float* __restrict__ outq)
{
  __shared__ float red[4];
  int b = blockIdx.x, t = TID;
  float num = 0.f;
  for (int i = 0; i < S2n; ++i) num += am[b * S2n + i];
  float pv = 0.f;
  if (t < Hn) {
    float s = 0.f;
    const float* sb = sf + (size_t)b * S2n * Hn + t;
    for (int q = 0; q < S2n; ++q) s += sb[(size_t)q * Hn];
    pv = Wv[t] * (s / num);
  }
  float val = block_reduce_sum(pv, red) + bv[0];
  const float* advb = adv + (size_t)b * S2n * Ln;
  float pa   = (t < S2n * Ln) ? advb[t] : 0.f;
  float mean = block_reduce_sum(pa, red) / (float)(S2n * Ln);
  for (int i = t; i < S2n * Ln; i += 256)
    outq[(size_t)b * S2n * Ln + i] = val + advb[i] - mean;
}

extern "C" void kernel_launch(void* const* d_in, const int* in_sizes, int n_in,
                              void* d_out, int out_size, void* d_ws, size_t ws_size,
                              hipStream_t stream)
{
  const float* states       = (const float*)d_in[0];
  const float* state_mask   = (const float*)d_in[1];
  const float* actions      = (const float*)d_in[2];
  const float* actions_mask = (const float*)d_in[3];
  const float* adj          = (const float*)d_in[4];
  const float* Wn  = (const float*)d_in[5];
  const float* bn  = (const float*)d_in[6];
  const float* Wu  = (const float*)d_in[7];
  const float* bu  = (const float*)d_in[8];
  const float* Wr  = (const float*)d_in[9];
  const float* br  = (const float*)d_in[10];
  const float* Wt  = (const float*)d_in[11];
  const float* bt  = (const float*)d_in[12];
  const float* Wa1 = (const float*)d_in[13];
  const float* ba1 = (const float*)d_in[14];
  const float* Wa2 = (const float*)d_in[15];
  const float* ba2 = (const float*)d_in[16];
  const float* Wv  = (const float*)d_in[17];
  const float* bvp = (const float*)d_in[18];
  const float* weight = (const float*)d_in[19];
  const float* bias   = (const float*)d_in[20];

  float* ws   = (float*)d_ws;
  float* h    = ws;                   // [8192][128]
  float* g    = ws + (1 << 20);       // [8192][384]
  float* kp   = ws + 6 * (1 << 20);   // [8192][128]
  float* qp   = ws + 7 * (1 << 20);   // [1024][128]
  float* E    = ws + 8 * (1 << 20);   // [16][64][512]
  float* sfb  = ws + 9 * (1 << 20);   // [16][64][128]
  float* adv  = sfb + 262144;         // [16][64][3]
  float* aux  = ws + 10 * (1 << 20);
  float* WtRT = aux;                  // [128][128]
  float* Wa1T = WtRT + 16384;         // [256][128] rows 0..127=TL,128..255=TR
  float* cu   = Wa1T + 32768;
  float* cr   = cu + 128;
  float* ct   = cr + 128;
  short* Bp   = (short*)(ws + 12 * (1 << 20));
  unsigned short* idx = (unsigned short*)(ws + 13 * (1 << 20));
  int* cnts   = (int*)(ws + 14 * (1 << 20));

  const int M = Bn * Sn;              // 8192

  prep1<<<2048 + 48, 256, 0, stream>>>(adj, idx, cnts, Wt, Wa1, WtRT, Wa1T);
  combine_pack<<<dim3(128, 3), 128, 0, stream>>>(Wn, Wu, Wr, Wt, bn, Bp,
                                                 cu, cr, ct);

  for (int step = 0; step < 3; ++step) {
    const float* hin = (step == 0) ? states : h;
    gemm_gf<<<dim3(M / 64, 3), 256, 0, stream>>>(hin, Bp, ct, g);
    int grid = (step == 0) ? 512 + 64 : 512;   // step 0 also computes qp
    adj_hh<<<grid, 256, 0, stream>>>(
        idx, cnts, g, hin, cu, cr, bu, br, WtRT, bt, h,
        step == 2 ? Wa1T + 16384 : nullptr, kp,
        actions, Wa1T, qp);
  }

  scores_exp_v3<<<dim3(Sn / 32, 2, Bn), 256, 0, stream>>>(
      qp, kp, ba1, Wa2, ba2, actions_mask, state_mask, E);
  fused_fg<<<dim3(S2n / 2, Bn), 256, 0, stream>>>(E, h, actions, weight,
                                                  bias, sfb, adv);
  final2_kernel<<<Bn, 256, 0, stream>>>(sfb, actions_mask, Wv, bvp, adv,
                                        (float*)d_out);
}

// Round 19
// 189.555 us; speedup vs baseline: 3.7883x; 1.2552x over previous
//
#include <hip/hip_runtime.h>
#include <math.h>

constexpr int Bn  = 16;
constexpr int Sn  = 512;
constexpr int S2n = 64;
constexpr int Hn  = 128;
constexpr int Ln  = 3;
constexpr int NNZ_CAP = 128;

#define TID ((int)threadIdx.x)

typedef __attribute__((ext_vector_type(8))) short bf16x8;
typedef __attribute__((ext_vector_type(4))) float f32x4;

__device__ inline float wave_reduce_sum(float v) {
#pragma unroll
  for (int off = 32; off > 0; off >>= 1) v += __shfl_xor(v, off, 64);
  return v;
}

__device__ inline float block_reduce_sum(float v, float* red) {
  v = wave_reduce_sum(v);
  int w  = TID >> 6;
  int nw = (int)blockDim.x >> 6;
  if ((TID & 63) == 0) red[w] = v;
  __syncthreads();
  float s = 0.f;
  for (int i = 0; i < nw; ++i) s += red[i];
  __syncthreads();
  return s;
}

__device__ inline float sigm(float x) { return 1.f / (1.f + expf(-x)); }

__device__ inline unsigned short f2bf(float f) {
  unsigned int u = __float_as_uint(f);
  u = (u + 0x7fffu + ((u >> 16) & 1u)) >> 16;
  return (unsigned short)u;
}

// prep1: bid<2048 -> compact adjacency rows to index lists (binary adj).
// bid>=2048 -> 32x32 transpose tiles for WtRT (16) and Wa1T (32).
__global__ __launch_bounds__(256) void prep1(
    const float* __restrict__ adj,
    unsigned short* __restrict__ idx, int* __restrict__ cnts,
    const float* __restrict__ Wt, const float* __restrict__ Wa1,
    float* __restrict__ WtRT, float* __restrict__ Wa1T)
{
  __shared__ float t[32][33];
  int bid = blockIdx.x;
  if (bid < 2048) {
    int wid = TID >> 6, lane = TID & 63;
    int row = bid * 4 + wid;
    const float* ar = adj + (size_t)row * Sn;
    unsigned short* out = idx + (size_t)row * NNZ_CAP;
    int base = 0;
    for (int j0 = 0; j0 < Sn; j0 += 64) {
      float av = ar[j0 + lane];
      unsigned long long mask = __ballot(av != 0.f);
      int pos = __popcll(mask & ((1ull << lane) - 1ull));
      if (av != 0.f) out[base + pos] = (unsigned short)(j0 + lane);
      base += __popcll(mask);
    }
    if (lane == 0) cnts[row] = base;
    return;
  }
  int flat = bid - 2048;
  const float* src; float* dst; int k0, n0, woff;
  if (flat < 16) { src = Wt;  dst = WtRT; k0 = (flat & 3) * 32; n0 = (flat >> 2) * 32; woff = 128; }
  else { int f2 = flat - 16; src = Wa1; dst = Wa1T; k0 = (f2 & 7) * 32; n0 = (f2 >> 3) * 32; woff = 0; }
  int tx = TID & 31, ty = TID >> 5;
#pragma unroll
  for (int i = 0; i < 32; i += 8)
    t[ty + i][tx] = src[(size_t)(n0 + ty + i) * 256 + woff + k0 + tx];
  __syncthreads();
#pragma unroll
  for (int i = 0; i < 32; i += 8)
    dst[(size_t)(k0 + ty + i) * 128 + n0 + tx] = t[tx][ty + i];
}

// Combined matrices packed to bf16 MFMA B-fragments; cvec[n] = bn . W[n,:128].
__global__ __launch_bounds__(128) void combine_pack(
    const float* __restrict__ Wn, const float* __restrict__ Wu,
    const float* __restrict__ Wr, const float* __restrict__ Wt,
    const float* __restrict__ bn, short* __restrict__ Bp,
    float* __restrict__ cu, float* __restrict__ cr, float* __restrict__ ct)
{
  int n = blockIdx.x, mat = blockIdx.y;
  const float* W = (mat == 0) ? Wu : (mat == 1) ? Wr : Wt;
  float* cv = (mat == 0) ? cu : (mat == 1) ? cr : ct;
  __shared__ float Ws[128], bns[128];
  __shared__ float red[2];
  int k = TID;
  Ws[k]  = W[(size_t)n * 256 + k];
  bns[k] = bn[k];
  __syncthreads();
  float acc = 0.f;
#pragma unroll 4
  for (int c = 0; c < 128; ++c)
    acc = fmaf(Wn[(size_t)c * 128 + k], Ws[c], acc);
  if (mat < 2) acc += W[(size_t)n * 256 + 128 + k];
  int idx2 = ((mat * 8 + (n >> 4)) * 4 + (k >> 5)) * 512 +
             (((k & 31) >> 3) * 16 + (n & 15)) * 8 + (k & 7);
  Bp[idx2] = (short)f2bf(acc);
  float pv = bns[k] * Ws[k];
  pv = wave_reduce_sum(pv);
  if ((k & 63) == 0) red[k >> 6] = pv;
  __syncthreads();
  if (k == 0) cv[n] = red[0] + red[1];
}

// MFMA bf16 gemm: g[row][mat*128+n] = h @ G_mat (+ct for mat 2).
// XCD-pinned: bid.x = tt*16 + b  (bid%8 == b%8 -> batch b stays on one XCD).
__global__ __launch_bounds__(256) void gemm_gf(
    const float* __restrict__ h, const short* __restrict__ Bp,
    const float* __restrict__ ctv, float* __restrict__ g)
{
  int w = TID >> 6, l = TID & 63;
  int x = blockIdx.x;
  int b = x & 15, tt = x >> 4;               // tt in [0,8)
  int r0 = b * 512 + tt * 64 + w * 16;
  int mat = blockIdx.y;
  const float* abase = h + (size_t)(r0 + (l & 15)) * 128 + (l >> 4) * 8;
  bf16x8 a[4];
#pragma unroll
  for (int kc = 0; kc < 4; ++kc) {
    float4 f0 = *(const float4*)(abase + kc * 32);
    float4 f1 = *(const float4*)(abase + kc * 32 + 4);
    bf16x8 v;
    v[0] = (short)f2bf(f0.x); v[1] = (short)f2bf(f0.y);
    v[2] = (short)f2bf(f0.z); v[3] = (short)f2bf(f0.w);
    v[4] = (short)f2bf(f1.x); v[5] = (short)f2bf(f1.y);
    v[6] = (short)f2bf(f1.z); v[7] = (short)f2bf(f1.w);
    a[kc] = v;
  }
  f32x4 acc[8];
#pragma unroll
  for (int nt = 0; nt < 8; ++nt) acc[nt] = (f32x4){0.f, 0.f, 0.f, 0.f};
  const short* bbase = Bp + (size_t)(mat * 8) * 4 * 512 + l * 8;
#pragma unroll
  for (int nt = 0; nt < 8; ++nt)
#pragma unroll
    for (int kc = 0; kc < 4; ++kc) {
      bf16x8 bb = *(const bf16x8*)(bbase + (nt * 4 + kc) * 512);
      acc[nt] = __builtin_amdgcn_mfma_f32_16x16x32_bf16(a[kc], bb, acc[nt], 0, 0, 0);
    }
  int col0 = l & 15, rb2 = (l >> 4) * 4;
  float* gout = g + (size_t)(r0 + rb2) * 384 + mat * 128 + col0;
#pragma unroll
  for (int nt = 0; nt < 8; ++nt) {
    float cadd = (mat == 2) ? ctv[nt * 16 + col0] : 0.f;
#pragma unroll
    for (int r = 0; r < 4; ++r)
      gout[(size_t)r * 384 + nt * 16] = acc[nt][r] + cadd;
  }
}

// Sparse gather gates, 1 row/wave (8192 waves). XCD-pinned: bid = tl*16 + b.
__global__ __launch_bounds__(256) void adj_gate(
    const unsigned short* __restrict__ idx, const int* __restrict__ cnts,
    const float* __restrict__ g, const float* __restrict__ h,
    const float* __restrict__ cu, const float* __restrict__ cr,
    const float* __restrict__ bu, const float* __restrict__ br,
    float* __restrict__ z, float* __restrict__ rh)
{
  int bid = blockIdx.x;
  int b = bid & 15, tl = bid >> 4;           // tl in [0,128)
  int wid = TID >> 6, lane = TID & 63;
  int i = tl * 4 + wid;
  size_t row = (size_t)b * Sn + i;
  int c = (lane < 32) ? 4 * lane : 128 + 4 * (lane - 32);
  const float* gb = g + (size_t)b * Sn * 384 + c;
  const unsigned short* ix = idx + row * NNZ_CAP;
  int cnt = cnts[row];
  float4 acc = {0.f, 0.f, 0.f, 0.f};
  int n = 0;
  for (; n + 4 <= cnt; n += 4) {
    ushort4 jj = *(const ushort4*)(ix + n);
    float4 x0 = *(const float4*)(gb + (size_t)jj.x * 384);
    float4 x1 = *(const float4*)(gb + (size_t)jj.y * 384);
    float4 x2 = *(const float4*)(gb + (size_t)jj.z * 384);
    float4 x3 = *(const float4*)(gb + (size_t)jj.w * 384);
    acc.x += (x0.x + x1.x) + (x2.x + x3.x);
    acc.y += (x0.y + x1.y) + (x2.y + x3.y);
    acc.z += (x0.z + x1.z) + (x2.z + x3.z);
    acc.w += (x0.w + x1.w) + (x2.w + x3.w);
  }
  for (; n < cnt; ++n) {
    int j = ix[n];
    float4 x = *(const float4*)(gb + (size_t)j * 384);
    acc.x += x.x; acc.y += x.y; acc.z += x.z; acc.w += x.w;
  }
  float d = (float)cnt;
  int cc = (lane < 32) ? 4 * lane : 4 * (lane - 32);
  const float* cvp = (lane < 32) ? cu : cr;
  const float* bvp = (lane < 32) ? bu : br;
  float4 cv = *(const float4*)(cvp + cc);
  float4 bv = *(const float4*)(bvp + cc);
  float4 sg;
  sg.x = sigm(acc.x + d * cv.x + bv.x);
  sg.y = sigm(acc.y + d * cv.y + bv.y);
  sg.z = sigm(acc.z + d * cv.z + bv.z);
  sg.w = sigm(acc.w + d * cv.w + bv.w);
  if (lane < 32) {
    *(float4*)(z + row * 128 + cc) = sg;
  } else {
    float4 hv = *(const float4*)(h + row * 128 + cc);
    sg.x *= hv.x; sg.y *= hv.y; sg.z *= hv.z; sg.w *= hv.w;
    *(float4*)(rh + row * 128 + cc) = sg;
  }
}

// h_new = h + z*(tanh(rh@WtRT + g_t + bt) - h); optional kp epilogue.
// bid<512: XCD-pinned tile (b = bid&15, tile = bid>>4). bid>=512: qp gemm.
__global__ __launch_bounds__(256) void gemm_hh(
    const float* __restrict__ rh, const float* __restrict__ g,
    const float* __restrict__ WtRT, const float* __restrict__ bt,
    const float* __restrict__ z, const float* __restrict__ h_in,
    float* __restrict__ h_out,
    const float* __restrict__ WeT, float* __restrict__ e_out,
    const float* __restrict__ qX, const float* __restrict__ qWT,
    float* __restrict__ qY)
{
  __shared__ float Xs[16 * 128];
  int bid = blockIdx.x;
  int t = TID;
  int c4 = (t & 31) * 4;
  int rb = (t >> 5) * 2;

  if (bid >= 512) {
    int r0 = (bid - 512) * 16;
    const float* xsrc = qX + (size_t)r0 * 128;
    for (int i = t; i < 512; i += 256)
      ((float4*)Xs)[i] = ((const float4*)xsrc)[i];
    __syncthreads();
    float acc[2][4] = {};
#pragma unroll 4
    for (int k = 0; k < 128; k += 4) {
      const float* wk = qWT + (size_t)k * 128 + c4;
      float4 w0 = *(const float4*)(wk);
      float4 w1 = *(const float4*)(wk + 128);
      float4 w2 = *(const float4*)(wk + 256);
      float4 w3 = *(const float4*)(wk + 384);
#pragma unroll
      for (int r = 0; r < 2; ++r) {
        float4 x = *(const float4*)&Xs[(rb + r) * 128 + k];
        acc[r][0] = fmaf(x.x, w0.x, acc[r][0]); acc[r][0] = fmaf(x.y, w1.x, acc[r][0]);
        acc[r][0] = fmaf(x.z, w2.x, acc[r][0]); acc[r][0] = fmaf(x.w, w3.x, acc[r][0]);
        acc[r][1] = fmaf(x.x, w0.y, acc[r][1]); acc[r][1] = fmaf(x.y, w1.y, acc[r][1]);
        acc[r][1] = fmaf(x.z, w2.y, acc[r][1]); acc[r][1] = fmaf(x.w, w3.y, acc[r][1]);
        acc[r][2] = fmaf(x.x, w0.z, acc[r][2]); acc[r][2] = fmaf(x.y, w1.z, acc[r][2]);
        acc[r][2] = fmaf(x.z, w2.z, acc[r][2]); acc[r][2] = fmaf(x.w, w3.z, acc[r][2]);
        acc[r][3] = fmaf(x.x, w0.w, acc[r][3]); acc[r][3] = fmaf(x.y, w1.w, acc[r][3]);
        acc[r][3] = fmaf(x.z, w2.w, acc[r][3]); acc[r][3] = fmaf(x.w, w3.w, acc[r][3]);
      }
    }
#pragma unroll
    for (int r = 0; r < 2; ++r) {
      float4 v = {acc[r][0], acc[r][1], acc[r][2], acc[r][3]};
      *(float4*)(qY + (size_t)(r0 + rb + r) * 128 + c4) = v;
    }
    return;
  }

  int b = bid & 15, tile = bid >> 4;         // tile in [0,32)
  int r0 = b * 512 + tile * 16;
  const float* xsrc = rh + (size_t)r0 * 128;
  for (int i = t; i < 512; i += 256)
    ((float4*)Xs)[i] = ((const float4*)xsrc)[i];
  __syncthreads();
  float acc[2][4] = {};
#pragma unroll 4
  for (int k = 0; k < 128; k += 4) {
    const float* wk = WtRT + (size_t)k * 128 + c4;
    float4 w0 = *(const float4*)(wk);
    float4 w1 = *(const float4*)(wk + 128);
    float4 w2 = *(const float4*)(wk + 256);
    float4 w3 = *(const float4*)(wk + 384);
#pragma unroll
    for (int r = 0; r < 2; ++r) {
      float4 x = *(const float4*)&Xs[(rb + r) * 128 + k];
      acc[r][0] = fmaf(x.x, w0.x, acc[r][0]); acc[r][0] = fmaf(x.y, w1.x, acc[r][0]);
      acc[r][0] = fmaf(x.z, w2.x, acc[r][0]); acc[r][0] = fmaf(x.w, w3.x, acc[r][0]);
      acc[r][1] = fmaf(x.x, w0.y, acc[r][1]); acc[r][1] = fmaf(x.y, w1.y, acc[r][1]);
      acc[r][1] = fmaf(x.z, w2.y, acc[r][1]); acc[r][1] = fmaf(x.w, w3.y, acc[r][1]);
      acc[r][2] = fmaf(x.x, w0.z, acc[r][2]); acc[r][2] = fmaf(x.y, w1.z, acc[r][2]);
      acc[r][2] = fmaf(x.z, w2.z, acc[r][2]); acc[r][2] = fmaf(x.w, w3.z, acc[r][2]);
      acc[r][3] = fmaf(x.x, w0.w, acc[r][3]); acc[r][3] = fmaf(x.y, w1.w, acc[r][3]);
      acc[r][3] = fmaf(x.z, w2.w, acc[r][3]); acc[r][3] = fmaf(x.w, w3.w, acc[r][3]);
    }
  }
  float4 btv = *(const float4*)(bt + c4);
  float hn[2][4];
#pragma unroll
  for (int r = 0; r < 2; ++r) {
    size_t row = r0 + rb + r;
    float4 gt = *(const float4*)(g + row * 384 + 256 + c4);
    float4 hv = *(const float4*)(h_in + row * 128 + c4);
    float4 zv = *(const float4*)(z + row * 128 + c4);
    hn[r][0] = hv.x + zv.x * (tanhf(acc[r][0] + gt.x + btv.x) - hv.x);
    hn[r][1] = hv.y + zv.y * (tanhf(acc[r][1] + gt.y + btv.y) - hv.y);
    hn[r][2] = hv.z + zv.z * (tanhf(acc[r][2] + gt.z + btv.z) - hv.z);
    hn[r][3] = hv.w + zv.w * (tanhf(acc[r][3] + gt.w + btv.w) - hv.w);
    float4 o = {hn[r][0], hn[r][1], hn[r][2], hn[r][3]};
    *(float4*)(h_out + row * 128 + c4) = o;
  }
  if (WeT) {
    __syncthreads();
#pragma unroll
    for (int r = 0; r < 2; ++r) {
      float4 o = {hn[r][0], hn[r][1], hn[r][2], hn[r][3]};
      *(float4*)&Xs[(rb + r) * 128 + c4] = o;
    }
    __syncthreads();
    float acc2[2][4] = {};
#pragma unroll 4
    for (int k = 0; k < 128; k += 4) {
      const float* wk = WeT + (size_t)k * 128 + c4;
      float4 w0 = *(const float4*)(wk);
      float4 w1 = *(const float4*)(wk + 128);
      float4 w2 = *(const float4*)(wk + 256);
      float4 w3 = *(const float4*)(wk + 384);
#pragma unroll
      for (int r = 0; r < 2; ++r) {
        float4 x = *(const float4*)&Xs[(rb + r) * 128 + k];
        acc2[r][0] = fmaf(x.x, w0.x, acc2[r][0]); acc2[r][0] = fmaf(x.y, w1.x, acc2[r][0]);
        acc2[r][0] = fmaf(x.z, w2.x, acc2[r][0]); acc2[r][0] = fmaf(x.w, w3.x, acc2[r][0]);
        acc2[r][1] = fmaf(x.x, w0.y, acc2[r][1]); acc2[r][1] = fmaf(x.y, w1.y, acc2[r][1]);
        acc2[r][1] = fmaf(x.z, w2.y, acc2[r][1]); acc2[r][1] = fmaf(x.w, w3.y, acc2[r][1]);
        acc2[r][2] = fmaf(x.x, w0.z, acc2[r][2]); acc2[r][2] = fmaf(x.y, w1.z, acc2[r][2]);
        acc2[r][2] = fmaf(x.z, w2.z, acc2[r][2]); acc2[r][2] = fmaf(x.w, w3.z, acc2[r][2]);
        acc2[r][3] = fmaf(x.x, w0.w, acc2[r][3]); acc2[r][3] = fmaf(x.y, w1.w, acc2[r][3]);
        acc2[r][3] = fmaf(x.z, w2.w, acc2[r][3]); acc2[r][3] = fmaf(x.w, w3.w, acc2[r][3]);
      }
    }
#pragma unroll
    for (int r = 0; r < 2; ++r) {
      float4 v = {acc2[r][0], acc2[r][1], acc2[r][2], acc2[r][3]};
      *(float4*)(e_out + (size_t)(r0 + rb + r) * 128 + c4) = v;
    }
  }
}

// E[b,q,k] = mask ? exp(relu(Wa2 . relu(qp[b,q]+kp[b,k]+ba1) + ba2)) : 0
__global__ __launch_bounds__(256) void scores_exp_v3(
    const float* __restrict__ qp, const float* __restrict__ kp,
    const float* __restrict__ ba1, const float* __restrict__ Wa2,
    const float* __restrict__ ba2, const float* __restrict__ am,
    const float* __restrict__ smk, float* __restrict__ E)
{
  constexpr int KT = 32, QT = 32;
  __shared__ float qs[QT][132];
  __shared__ float ks[KT][132];
  __shared__ float w2s[128];
  __shared__ float es[QT][33];
  int b = blockIdx.z, kt = blockIdx.x * KT, qt = blockIdx.y * QT;
  const float* qsrc = qp + ((size_t)b * S2n + qt) * Hn;
  for (int f = TID; f < QT * 32; f += 256) {
    int q = f >> 5, g = f & 31;
    float4 v  = ((const float4*)qsrc)[f];
    float4 bb = ((const float4*)ba1)[g];
    v.x += bb.x; v.y += bb.y; v.z += bb.z; v.w += bb.w;
    *(float4*)&qs[q][4 * g] = v;
  }
  const float* ksrc = kp + ((size_t)b * Sn + kt) * Hn;
  for (int f = TID; f < KT * 32; f += 256) {
    int k = f >> 5, g = f & 31;
    *(float4*)&ks[k][4 * g] = ((const float4*)ksrc)[f];
  }
  if (TID < 128) w2s[TID] = Wa2[TID];
  __syncthreads();
  const int q0 = (TID & 15) * 2;
  const int k0 = (TID >> 4) * 2;
  float acc[2][2] = {};
#pragma unroll 4
  for (int h = 0; h < 128; ++h) {
    float w  = w2s[h];
    float kv0 = ks[k0][h], kv1 = ks[k0 + 1][h];
    float qv0 = qs[q0][h], qv1 = qs[q0 + 1][h];
    acc[0][0] = fmaf(fmaxf(qv0 + kv0, 0.f), w, acc[0][0]);
    acc[0][1] = fmaf(fmaxf(qv0 + kv1, 0.f), w, acc[0][1]);
    acc[1][0] = fmaf(fmaxf(qv1 + kv0, 0.f), w, acc[1][0]);
    acc[1][1] = fmaf(fmaxf(qv1 + kv1, 0.f), w, acc[1][1]);
  }
  float b2 = ba2[0];
#pragma unroll
  for (int i = 0; i < 2; ++i) {
    float amq = am[b * S2n + qt + q0 + i];
#pragma unroll
    for (int j = 0; j < 2; ++j) {
      float m = amq * smk[b * Sn + kt + k0 + j];
      float s = fmaxf(acc[i][j] + b2, 0.f);
      es[q0 + i][k0 + j] = (m > 0.f) ? expf(s) : 0.f;
    }
  }
  __syncthreads();
  float* Eb = E + ((size_t)b * S2n + qt) * Sn + kt;
  for (int f = TID; f < QT * KT; f += 256) {
    int q = f >> 5, kin = f & 31;
    Eb[(size_t)q * Sn + kin] = es[q][kin];
  }
}

// Fused attn weighted sum + adv: block = (q-pair, b); 128 threads per q.
__global__ __launch_bounds__(256) void fused_fg(
    const float* __restrict__ E, const float* __restrict__ h,
    const float* __restrict__ actions, const float* __restrict__ weight,
    const float* __restrict__ bias, float* __restrict__ sf,
    float* __restrict__ adv)
{
  __shared__ float Es[2][512];
  __shared__ float red[4];
  __shared__ float sfs[2][128];
  __shared__ float acts[2][128];
  __shared__ float redl[4];
  int b = blockIdx.y;
  int t = TID, lane = t & 63, wv = t >> 6;
  int half = t >> 7, tloc = t & 127;
  int q = blockIdx.x * 2 + half;
  size_t rowq = (size_t)b * S2n + q;
  const float* Erow = E + rowq * Sn;
  for (int i = tloc; i < Sn; i += 128) Es[half][i] = Erow[i];
  __syncthreads();
  float part = Es[half][tloc] + Es[half][tloc + 128] +
               Es[half][tloc + 256] + Es[half][tloc + 384];
  part = wave_reduce_sum(part);
  if (lane == 0) red[wv] = part;
  __syncthreads();
  float scale = 1.f / fmaxf(red[half * 2] + red[half * 2 + 1], 2e-15f);
  const float* ob = h + (size_t)b * Sn * Hn + tloc;
  float acc = 0.f;
#pragma unroll 8
  for (int k = 0; k < Sn; ++k)
    acc = fmaf(Es[half][k], ob[(size_t)k * Hn], acc);
  float sfv = acc * scale;
  sf[rowq * Hn + tloc] = sfv;
  sfs[half][tloc]  = sfv;
  acts[half][tloc] = actions[rowq * Hn + tloc];
  __syncthreads();
  for (int l = 0; l < Ln; ++l) {
    const float* wr = weight + ((size_t)l * Hn + tloc) * Hn;
    float tmp = 0.f;
#pragma unroll 4
    for (int k = 0; k < Hn; k += 4) {
      float4 wv4 = *(const float4*)(wr + k);
      tmp = fmaf(wv4.x, sfs[half][k],     tmp);
      tmp = fmaf(wv4.y, sfs[half][k + 1], tmp);
      tmp = fmaf(wv4.z, sfs[half][k + 2], tmp);
      tmp = fmaf(wv4.w, sfs[half][k + 3], tmp);
    }
    float pa = acts[half][tloc] * tmp;
    pa = wave_reduce_sum(pa);
    if (lane == 0) redl[wv] = pa;
    __syncthreads();
    float tot = redl[half * 2] + redl[half * 2 + 1];
    if (tloc == 0) adv[rowq * Ln + l] = tot + bias[l];
    __syncthreads();
  }
}

// Fused: sem = mean_q sf ; val = Wv.sem+bv ; q = val + adv - mean(adv)
__global__ __launch_bounds__(256) void final2_kernel(
    const float* __restrict__ sf, const float* __restrict__ am,
    const float* __restrict__ Wv, const float* __restrict__ bv,
    const float* __restrict__ adv, float* __restrict__ outq)
{
  __shared__ float red[4];
  int b = blockIdx.x, t = TID;
  float num = 0.f;
  for (int i = 0; i < S2n; ++i) num += am[b * S2n + i];
  float pv = 0.f;
  if (t < Hn) {
    float s = 0.f;
    const float* sb = sf + (size_t)b * S2n * Hn + t;
    for (int q = 0; q < S2n; ++q) s += sb[(size_t)q * Hn];
    pv = Wv[t] * (s / num);
  }
  float val = block_reduce_sum(pv, red) + bv[0];
  const float* advb = adv + (size_t)b * S2n * Ln;
  float pa   = (t < S2n * Ln) ? advb[t] : 0.f;
  float mean = block_reduce_sum(pa, red) / (float)(S2n * Ln);
  for (int i = t; i < S2n * Ln; i += 256)
    outq[(size_t)b * S2n * Ln + i] = val + advb[i] - mean;
}

extern "C" void kernel_launch(void* const* d_in, const int* in_sizes, int n_in,
                              void* d_out, int out_size, void* d_ws, size_t ws_size,
                              hipStream_t stream)
{
  const float* states       = (const float*)d_in[0];
  const float* state_mask   = (const float*)d_in[1];
  const float* actions      = (const float*)d_in[2];
  const float* actions_mask = (const float*)d_in[3];
  const float* adj          = (const float*)d_in[4];
  const float* Wn  = (const float*)d_in[5];
  const float* bn  = (const float*)d_in[6];
  const float* Wu  = (const float*)d_in[7];
  const float* bu  = (const float*)d_in[8];
  const float* Wr  = (const float*)d_in[9];
  const float* br  = (const float*)d_in[10];
  const float* Wt  = (const float*)d_in[11];
  const float* bt  = (const float*)d_in[12];
  const float* Wa1 = (const float*)d_in[13];
  const float* ba1 = (const float*)d_in[14];
  const float* Wa2 = (const float*)d_in[15];
  const float* ba2 = (const float*)d_in[16];
  const float* Wv  = (const float*)d_in[17];
  const float* bvp = (const float*)d_in[18];
  const float* weight = (const float*)d_in[19];
  const float* bias   = (const float*)d_in[20];

  float* ws   = (float*)d_ws;
  float* h    = ws;                   // [8192][128]
  float* g    = ws + (1 << 20);       // [8192][384]
  float* zp   = ws + 4 * (1 << 20);   // [8192][128]
  float* rh   = ws + 5 * (1 << 20);   // [8192][128]
  float* kp   = ws + 6 * (1 << 20);   // [8192][128]
  float* qp   = ws + 7 * (1 << 20);   // [1024][128]
  float* E    = ws + 8 * (1 << 20);   // [16][64][512]
  float* sfb  = ws + 9 * (1 << 20);   // [16][64][128]
  float* adv  = sfb + 262144;         // [16][64][3]
  float* aux  = ws + 10 * (1 << 20);
  float* WtRT = aux;                  // [128][128]
  float* Wa1T = WtRT + 16384;         // [256][128] rows 0..127=TL,128..255=TR
  float* cu   = Wa1T + 32768;
  float* cr   = cu + 128;
  float* ct   = cr + 128;
  short* Bp   = (short*)(ws + 12 * (1 << 20));
  unsigned short* idx = (unsigned short*)(ws + 13 * (1 << 20));
  int* cnts   = (int*)(ws + 14 * (1 << 20));

  prep1<<<2048 + 48, 256, 0, stream>>>(adj, idx, cnts, Wt, Wa1, WtRT, Wa1T);
  combine_pack<<<dim3(128, 3), 128, 0, stream>>>(Wn, Wu, Wr, Wt, bn, Bp,
                                                 cu, cr, ct);

  for (int step = 0; step < 3; ++step) {
    const float* hin = (step == 0) ? states : h;
    gemm_gf<<<dim3(128, 3), 256, 0, stream>>>(hin, Bp, ct, g);
    adj_gate<<<2048, 256, 0, stream>>>(idx, cnts, g, hin,
                                       cu, cr, bu, br, zp, rh);
    int grid = (step == 0) ? 512 + 64 : 512;   // step 0 also computes qp
    gemm_hh<<<grid, 256, 0, stream>>>(
        rh, g, WtRT, bt, zp, hin, h,
        step == 2 ? Wa1T + 16384 : nullptr, kp,
        actions, Wa1T, qp);
  }

  scores_exp_v3<<<dim3(Sn / 32, 2, Bn), 256, 0, stream>>>(
      qp, kp, ba1, Wa2, ba2, actions_mask, state_mask, E);
  fused_fg<<<dim3(S2n / 2, Bn), 256, 0, stream>>>(E, h, actions, weight,
                                                  bias, sfb, adv);
  final2_kernel<<<Bn, 256, 0, stream>>>(sfb, actions_mask, Wv, bvp, adv,
                                        (float*)d_out);
}

// Round 21
// 178.630 us; speedup vs baseline: 4.0200x; 1.0612x over previous
//
#include <hip/hip_runtime.h>
#include <math.h>

constexpr int Bn  = 16;
constexpr int Sn  = 512;
constexpr int S2n = 64;
constexpr int Hn  = 128;
constexpr int Ln  = 3;
constexpr int NNZ_CAP = 128;

#define TID ((int)threadIdx.x)

typedef __attribute__((ext_vector_type(8))) short bf16x8;
typedef __attribute__((ext_vector_type(4))) float f32x4;

__device__ inline float wave_reduce_sum(float v) {
#pragma unroll
  for (int off = 32; off > 0; off >>= 1) v += __shfl_xor(v, off, 64);
  return v;
}

__device__ inline float block_reduce_sum(float v, float* red) {
  v = wave_reduce_sum(v);
  int w  = TID >> 6;
  int nw = (int)blockDim.x >> 6;
  if ((TID & 63) == 0) red[w] = v;
  __syncthreads();
  float s = 0.f;
  for (int i = 0; i < nw; ++i) s += red[i];
  __syncthreads();
  return s;
}

__device__ inline float sigm(float x) { return 1.f / (1.f + expf(-x)); }

__device__ inline unsigned short f2bf(float f) {
  unsigned int u = __float_as_uint(f);
  u = (u + 0x7fffu + ((u >> 16) & 1u)) >> 16;
  return (unsigned short)u;
}

// prep1: bid<2048 -> compact adjacency rows to index lists (binary adj).
// bid>=2048 -> 32x32 transpose tiles for WtRT (16) and Wa1T (32).
__global__ __launch_bounds__(256) void prep1(
    const float* __restrict__ adj,
    unsigned short* __restrict__ idx, int* __restrict__ cnts,
    const float* __restrict__ Wt, const float* __restrict__ Wa1,
    float* __restrict__ WtRT, float* __restrict__ Wa1T)
{
  __shared__ float t[32][33];
  int bid = blockIdx.x;
  if (bid < 2048) {
    int wid = TID >> 6, lane = TID & 63;
    int row = bid * 4 + wid;
    const float* ar = adj + (size_t)row * Sn;
    unsigned short* out = idx + (size_t)row * NNZ_CAP;
    int base = 0;
    for (int j0 = 0; j0 < Sn; j0 += 64) {
      float av = ar[j0 + lane];
      unsigned long long mask = __ballot(av != 0.f);
      int pos = __popcll(mask & ((1ull << lane) - 1ull));
      if (av != 0.f) out[base + pos] = (unsigned short)(j0 + lane);
      base += __popcll(mask);
    }
    if (lane == 0) cnts[row] = base;
    return;
  }
  int flat = bid - 2048;
  const float* src; float* dst; int k0, n0, woff;
  if (flat < 16) { src = Wt;  dst = WtRT; k0 = (flat & 3) * 32; n0 = (flat >> 2) * 32; woff = 128; }
  else { int f2 = flat - 16; src = Wa1; dst = Wa1T; k0 = (f2 & 7) * 32; n0 = (f2 >> 3) * 32; woff = 0; }
  int tx = TID & 31, ty = TID >> 5;
#pragma unroll
  for (int i = 0; i < 32; i += 8)
    t[ty + i][tx] = src[(size_t)(n0 + ty + i) * 256 + woff + k0 + tx];
  __syncthreads();
#pragma unroll
  for (int i = 0; i < 32; i += 8)
    dst[(size_t)(k0 + ty + i) * 128 + n0 + tx] = t[tx][ty + i];
}

// Combined matrices packed to bf16 MFMA B-fragments; cvec[n] = bn . W[n,:128].
__global__ __launch_bounds__(128) void combine_pack(
    const float* __restrict__ Wn, const float* __restrict__ Wu,
    const float* __restrict__ Wr, const float* __restrict__ Wt,
    const float* __restrict__ bn, short* __restrict__ Bp,
    float* __restrict__ cu, float* __restrict__ cr, float* __restrict__ ct)
{
  int n = blockIdx.x, mat = blockIdx.y;
  const float* W = (mat == 0) ? Wu : (mat == 1) ? Wr : Wt;
  float* cv = (mat == 0) ? cu : (mat == 1) ? cr : ct;
  __shared__ float Ws[128], bns[128];
  __shared__ float red[2];
  int k = TID;
  Ws[k]  = W[(size_t)n * 256 + k];
  bns[k] = bn[k];
  __syncthreads();
  float acc = 0.f;
#pragma unroll 4
  for (int c = 0; c < 128; ++c)
    acc = fmaf(Wn[(size_t)c * 128 + k], Ws[c], acc);
  if (mat < 2) acc += W[(size_t)n * 256 + 128 + k];
  int idx2 = ((mat * 8 + (n >> 4)) * 4 + (k >> 5)) * 512 +
             (((k & 31) >> 3) * 16 + (n & 15)) * 8 + (k & 7);
  Bp[idx2] = (short)f2bf(acc);
  float pv = bns[k] * Ws[k];
  pv = wave_reduce_sum(pv);
  if ((k & 63) == 0) red[k >> 6] = pv;
  __syncthreads();
  if (k == 0) cv[n] = red[0] + red[1];
}

// MFMA bf16 gemm: g[row][mat*128+n] = h @ G_mat (+ct for mat 2).
// XCD-pinned: bid.x = tt*16 + b.
__global__ __launch_bounds__(256) void gemm_gf(
    const float* __restrict__ h, const short* __restrict__ Bp,
    const float* __restrict__ ctv, float* __restrict__ g)
{
  int w = TID >> 6, l = TID & 63;
  int x = blockIdx.x;
  int b = x & 15, tt = x >> 4;
  int r0 = b * 512 + tt * 64 + w * 16;
  int mat = blockIdx.y;
  const float* abase = h + (size_t)(r0 + (l & 15)) * 128 + (l >> 4) * 8;
  bf16x8 a[4];
#pragma unroll
  for (int kc = 0; kc < 4; ++kc) {
    float4 f0 = *(const float4*)(abase + kc * 32);
    float4 f1 = *(const float4*)(abase + kc * 32 + 4);
    bf16x8 v;
    v[0] = (short)f2bf(f0.x); v[1] = (short)f2bf(f0.y);
    v[2] = (short)f2bf(f0.z); v[3] = (short)f2bf(f0.w);
    v[4] = (short)f2bf(f1.x); v[5] = (short)f2bf(f1.y);
    v[6] = (short)f2bf(f1.z); v[7] = (short)f2bf(f1.w);
    a[kc] = v;
  }
  f32x4 acc[8];
#pragma unroll
  for (int nt = 0; nt < 8; ++nt) acc[nt] = (f32x4){0.f, 0.f, 0.f, 0.f};
  const short* bbase = Bp + (size_t)(mat * 8) * 4 * 512 + l * 8;
#pragma unroll
  for (int nt = 0; nt < 8; ++nt)
#pragma unroll
    for (int kc = 0; kc < 4; ++kc) {
      bf16x8 bb = *(const bf16x8*)(bbase + (nt * 4 + kc) * 512);
      acc[nt] = __builtin_amdgcn_mfma_f32_16x16x32_bf16(a[kc], bb, acc[nt], 0, 0, 0);
    }
  int col0 = l & 15, rb2 = (l >> 4) * 4;
  float* gout = g + (size_t)(r0 + rb2) * 384 + mat * 128 + col0;
#pragma unroll
  for (int nt = 0; nt < 8; ++nt) {
    float cadd = (mat == 2) ? ctv[nt * 16 + col0] : 0.f;
#pragma unroll
    for (int r = 0; r < 4; ++r)
      gout[(size_t)r * 384 + nt * 16] = acc[nt][r] + cadd;
  }
}

// Sparse gather gates, 1 row/wave (8192 waves). XCD-pinned: bid = tl*16 + b.
__global__ __launch_bounds__(256) void adj_gate(
    const unsigned short* __restrict__ idx, const int* __restrict__ cnts,
    const float* __restrict__ g, const float* __restrict__ h,
    const float* __restrict__ cu, const float* __restrict__ cr,
    const float* __restrict__ bu, const float* __restrict__ br,
    float* __restrict__ z, float* __restrict__ rh)
{
  int bid = blockIdx.x;
  int b = bid & 15, tl = bid >> 4;
  int wid = TID >> 6, lane = TID & 63;
  int i = tl * 4 + wid;
  size_t row = (size_t)b * Sn + i;
  int c = (lane < 32) ? 4 * lane : 128 + 4 * (lane - 32);
  const float* gb = g + (size_t)b * Sn * 384 + c;
  const unsigned short* ix = idx + row * NNZ_CAP;
  int cnt = cnts[row];
  float4 acc = {0.f, 0.f, 0.f, 0.f};
  int n = 0;
  for (; n + 4 <= cnt; n += 4) {
    ushort4 jj = *(const ushort4*)(ix + n);
    float4 x0 = *(const float4*)(gb + (size_t)jj.x * 384);
    float4 x1 = *(const float4*)(gb + (size_t)jj.y * 384);
    float4 x2 = *(const float4*)(gb + (size_t)jj.z * 384);
    float4 x3 = *(const float4*)(gb + (size_t)jj.w * 384);
    acc.x += (x0.x + x1.x) + (x2.x + x3.x);
    acc.y += (x0.y + x1.y) + (x2.y + x3.y);
    acc.z += (x0.z + x1.z) + (x2.z + x3.z);
    acc.w += (x0.w + x1.w) + (x2.w + x3.w);
  }
  for (; n < cnt; ++n) {
    int j = ix[n];
    float4 x = *(const float4*)(gb + (size_t)j * 384);
    acc.x += x.x; acc.y += x.y; acc.z += x.z; acc.w += x.w;
  }
  float d = (float)cnt;
  int cc = (lane < 32) ? 4 * lane : 4 * (lane - 32);
  const float* cvp = (lane < 32) ? cu : cr;
  const float* bvp = (lane < 32) ? bu : br;
  float4 cv = *(const float4*)(cvp + cc);
  float4 bv = *(const float4*)(bvp + cc);
  float4 sg;
  sg.x = sigm(acc.x + d * cv.x + bv.x);
  sg.y = sigm(acc.y + d * cv.y + bv.y);
  sg.z = sigm(acc.z + d * cv.z + bv.z);
  sg.w = sigm(acc.w + d * cv.w + bv.w);
  if (lane < 32) {
    *(float4*)(z + row * 128 + cc) = sg;
  } else {
    float4 hv = *(const float4*)(h + row * 128 + cc);
    sg.x *= hv.x; sg.y *= hv.y; sg.z *= hv.z; sg.w *= hv.w;
    *(float4*)(rh + row * 128 + cc) = sg;
  }
}

// h_new = h + z*(tanh(rh@WtRT + g_t + bt) - h); optional kp epilogue.
// bid<512: XCD-pinned tile (b = bid&15, tile = bid>>4). bid>=512: qp gemm.
__global__ __launch_bounds__(256) void gemm_hh(
    const float* __restrict__ rh, const float* __restrict__ g,
    const float* __restrict__ WtRT, const float* __restrict__ bt,
    const float* __restrict__ z, const float* __restrict__ h_in,
    float* __restrict__ h_out,
    const float* __restrict__ WeT, float* __restrict__ e_out,
    const float* __restrict__ qX, const float* __restrict__ qWT,
    float* __restrict__ qY)
{
  __shared__ float Xs[16 * 128];
  int bid = blockIdx.x;
  int t = TID;
  int c4 = (t & 31) * 4;
  int rb = (t >> 5) * 2;

  if (bid >= 512) {
    int r0 = (bid - 512) * 16;
    const float* xsrc = qX + (size_t)r0 * 128;
    for (int i = t; i < 512; i += 256)
      ((float4*)Xs)[i] = ((const float4*)xsrc)[i];
    __syncthreads();
    float acc[2][4] = {};
#pragma unroll 4
    for (int k = 0; k < 128; k += 4) {
      const float* wk = qWT + (size_t)k * 128 + c4;
      float4 w0 = *(const float4*)(wk);
      float4 w1 = *(const float4*)(wk + 128);
      float4 w2 = *(const float4*)(wk + 256);
      float4 w3 = *(const float4*)(wk + 384);
#pragma unroll
      for (int r = 0; r < 2; ++r) {
        float4 x = *(const float4*)&Xs[(rb + r) * 128 + k];
        acc[r][0] = fmaf(x.x, w0.x, acc[r][0]); acc[r][0] = fmaf(x.y, w1.x, acc[r][0]);
        acc[r][0] = fmaf(x.z, w2.x, acc[r][0]); acc[r][0] = fmaf(x.w, w3.x, acc[r][0]);
        acc[r][1] = fmaf(x.x, w0.y, acc[r][1]); acc[r][1] = fmaf(x.y, w1.y, acc[r][1]);
        acc[r][1] = fmaf(x.z, w2.y, acc[r][1]); acc[r][1] = fmaf(x.w, w3.y, acc[r][1]);
        acc[r][2] = fmaf(x.x, w0.z, acc[r][2]); acc[r][2] = fmaf(x.y, w1.z, acc[r][2]);
        acc[r][2] = fmaf(x.z, w2.z, acc[r][2]); acc[r][2] = fmaf(x.w, w3.z, acc[r][2]);
        acc[r][3] = fmaf(x.x, w0.w, acc[r][3]); acc[r][3] = fmaf(x.y, w1.w, acc[r][3]);
        acc[r][3] = fmaf(x.z, w2.w, acc[r][3]); acc[r][3] = fmaf(x.w, w3.w, acc[r][3]);
      }
    }
#pragma unroll
    for (int r = 0; r < 2; ++r) {
      float4 v = {acc[r][0], acc[r][1], acc[r][2], acc[r][3]};
      *(float4*)(qY + (size_t)(r0 + rb + r) * 128 + c4) = v;
    }
    return;
  }

  int b = bid & 15, tile = bid >> 4;
  int r0 = b * 512 + tile * 16;
  const float* xsrc = rh + (size_t)r0 * 128;
  for (int i = t; i < 512; i += 256)
    ((float4*)Xs)[i] = ((const float4*)xsrc)[i];
  __syncthreads();
  float acc[2][4] = {};
#pragma unroll 4
  for (int k = 0; k < 128; k += 4) {
    const float* wk = WtRT + (size_t)k * 128 + c4;
    float4 w0 = *(const float4*)(wk);
    float4 w1 = *(const float4*)(wk + 128);
    float4 w2 = *(const float4*)(wk + 256);
    float4 w3 = *(const float4*)(wk + 384);
#pragma unroll
    for (int r = 0; r < 2; ++r) {
      float4 x = *(const float4*)&Xs[(rb + r) * 128 + k];
      acc[r][0] = fmaf(x.x, w0.x, acc[r][0]); acc[r][0] = fmaf(x.y, w1.x, acc[r][0]);
      acc[r][0] = fmaf(x.z, w2.x, acc[r][0]); acc[r][0] = fmaf(x.w, w3.x, acc[r][0]);
      acc[r][1] = fmaf(x.x, w0.y, acc[r][1]); acc[r][1] = fmaf(x.y, w1.y, acc[r][1]);
      acc[r][1] = fmaf(x.z, w2.y, acc[r][1]); acc[r][1] = fmaf(x.w, w3.y, acc[r][1]);
      acc[r][2] = fmaf(x.x, w0.z, acc[r][2]); acc[r][2] = fmaf(x.y, w1.z, acc[r][2]);
      acc[r][2] = fmaf(x.z, w2.z, acc[r][2]); acc[r][2] = fmaf(x.w, w3.z, acc[r][2]);
      acc[r][3] = fmaf(x.x, w0.w, acc[r][3]); acc[r][3] = fmaf(x.y, w1.w, acc[r][3]);
      acc[r][3] = fmaf(x.z, w2.w, acc[r][3]); acc[r][3] = fmaf(x.w, w3.w, acc[r][3]);
    }
  }
  float4 btv = *(const float4*)(bt + c4);
  float hn[2][4];
#pragma unroll
  for (int r = 0; r < 2; ++r) {
    size_t row = r0 + rb + r;
    float4 gt = *(const float4*)(g + row * 384 + 256 + c4);
    float4 hv = *(const float4*)(h_in + row * 128 + c4);
    float4 zv = *(const float4*)(z + row * 128 + c4);
    hn[r][0] = hv.x + zv.x * (tanhf(acc[r][0] + gt.x + btv.x) - hv.x);
    hn[r][1] = hv.y + zv.y * (tanhf(acc[r][1] + gt.y + btv.y) - hv.y);
    hn[r][2] = hv.z + zv.z * (tanhf(acc[r][2] + gt.z + btv.z) - hv.z);
    hn[r][3] = hv.w + zv.w * (tanhf(acc[r][3] + gt.w + btv.w) - hv.w);
    float4 o = {hn[r][0], hn[r][1], hn[r][2], hn[r][3]};
    *(float4*)(h_out + row * 128 + c4) = o;
  }
  if (WeT) {
    __syncthreads();
#pragma unroll
    for (int r = 0; r < 2; ++r) {
      float4 o = {hn[r][0], hn[r][1], hn[r][2], hn[r][3]};
      *(float4*)&Xs[(rb + r) * 128 + c4] = o;
    }
    __syncthreads();
    float acc2[2][4] = {};
#pragma unroll 4
    for (int k = 0; k < 128; k += 4) {
      const float* wk = WeT + (size_t)k * 128 + c4;
      float4 w0 = *(const float4*)(wk);
      float4 w1 = *(const float4*)(wk + 128);
      float4 w2 = *(const float4*)(wk + 256);
      float4 w3 = *(const float4*)(wk + 384);
#pragma unroll
      for (int r = 0; r < 2; ++r) {
        float4 x = *(const float4*)&Xs[(rb + r) * 128 + k];
        acc2[r][0] = fmaf(x.x, w0.x, acc2[r][0]); acc2[r][0] = fmaf(x.y, w1.x, acc2[r][0]);
        acc2[r][0] = fmaf(x.z, w2.x, acc2[r][0]); acc2[r][0] = fmaf(x.w, w3.x, acc2[r][0]);
        acc2[r][1] = fmaf(x.x, w0.y, acc2[r][1]); acc2[r][1] = fmaf(x.y, w1.y, acc2[r][1]);
        acc2[r][1] = fmaf(x.z, w2.y, acc2[r][1]); acc2[r][1] = fmaf(x.w, w3.y, acc2[r][1]);
        acc2[r][2] = fmaf(x.x, w0.z, acc2[r][2]); acc2[r][2] = fmaf(x.y, w1.z, acc2[r][2]);
        acc2[r][2] = fmaf(x.z, w2.z, acc2[r][2]); acc2[r][2] = fmaf(x.w, w3.z, acc2[r][2]);
        acc2[r][3] = fmaf(x.x, w0.w, acc2[r][3]); acc2[r][3] = fmaf(x.y, w1.w, acc2[r][3]);
        acc2[r][3] = fmaf(x.z, w2.w, acc2[r][3]); acc2[r][3] = fmaf(x.w, w3.w, acc2[r][3]);
      }
    }
#pragma unroll
    for (int r = 0; r < 2; ++r) {
      float4 v = {acc2[r][0], acc2[r][1], acc2[r][2], acc2[r][3]};
      *(float4*)(e_out + (size_t)(r0 + rb + r) * 128 + c4) = v;
    }
  }
}

// E[b,q,k] = mask ? exp(relu(Wa2 . relu(qp[b,q]+kp[b,k]+ba1) + ba2)) : 0
__global__ __launch_bounds__(256) void scores_exp_v3(
    const float* __restrict__ qp, const float* __restrict__ kp,
    const float* __restrict__ ba1, const float* __restrict__ Wa2,
    const float* __restrict__ ba2, const float* __restrict__ am,
    const float* __restrict__ smk, float* __restrict__ E)
{
  constexpr int KT = 32, QT = 32;
  __shared__ float qs[QT][132];
  __shared__ float ks[KT][132];
  __shared__ float w2s[128];
  __shared__ float es[QT][33];
  int b = blockIdx.z, kt = blockIdx.x * KT, qt = blockIdx.y * QT;
  const float* qsrc = qp + ((size_t)b * S2n + qt) * Hn;
  for (int f = TID; f < QT * 32; f += 256) {
    int q = f >> 5, g = f & 31;
    float4 v  = ((const float4*)qsrc)[f];
    float4 bb = ((const float4*)ba1)[g];
    v.x += bb.x; v.y += bb.y; v.z += bb.z; v.w += bb.w;
    *(float4*)&qs[q][4 * g] = v;
  }
  const float* ksrc = kp + ((size_t)b * Sn + kt) * Hn;
  for (int f = TID; f < KT * 32; f += 256) {
    int k = f >> 5, g = f & 31;
    *(float4*)&ks[k][4 * g] = ((const float4*)ksrc)[f];
  }
  if (TID < 128) w2s[TID] = Wa2[TID];
  __syncthreads();
  const int q0 = (TID & 15) * 2;
  const int k0 = (TID >> 4) * 2;
  float acc[2][2] = {};
#pragma unroll 4
  for (int h = 0; h < 128; ++h) {
    float w  = w2s[h];
    float kv0 = ks[k0][h], kv1 = ks[k0 + 1][h];
    float qv0 = qs[q0][h], qv1 = qs[q0 + 1][h];
    acc[0][0] = fmaf(fmaxf(qv0 + kv0, 0.f), w, acc[0][0]);
    acc[0][1] = fmaf(fmaxf(qv0 + kv1, 0.f), w, acc[0][1]);
    acc[1][0] = fmaf(fmaxf(qv1 + kv0, 0.f), w, acc[1][0]);
    acc[1][1] = fmaf(fmaxf(qv1 + kv1, 0.f), w, acc[1][1]);
  }
  float b2 = ba2[0];
#pragma unroll
  for (int i = 0; i < 2; ++i) {
    float amq = am[b * S2n + qt + q0 + i];
#pragma unroll
    for (int j = 0; j < 2; ++j) {
      float m = amq * smk[b * Sn + kt + k0 + j];
      float s = fmaxf(acc[i][j] + b2, 0.f);
      es[q0 + i][k0 + j] = (m > 0.f) ? expf(s) : 0.f;
    }
  }
  __syncthreads();
  float* Eb = E + ((size_t)b * S2n + qt) * Sn + kt;
  for (int f = TID; f < QT * KT; f += 256) {
    int q = f >> 5, kin = f & 31;
    Eb[(size_t)q * Sn + kin] = es[q][kin];
  }
}

// Fused attn weighted sum + adv, v2: flat XCD-pinned grid (b = bid&15),
// 4 independent k-chain accumulators for ILP.
__global__ __launch_bounds__(256) void fused_fg2(
    const float* __restrict__ E, const float* __restrict__ h,
    const float* __restrict__ actions, const float* __restrict__ weight,
    const float* __restrict__ bias, float* __restrict__ sf,
    float* __restrict__ adv)
{
  __shared__ float Es[2][512];
  __shared__ float red[4];
  __shared__ float sfs[2][128];
  __shared__ float acts[2][128];
  __shared__ float redl[4];
  int bid = blockIdx.x;
  int b = bid & 15, qpair = bid >> 4;        // qpair in [0,32)
  int t = TID, lane = t & 63, wv = t >> 6;
  int half = t >> 7, tloc = t & 127;
  int q = qpair * 2 + half;
  size_t rowq = (size_t)b * S2n + q;
  const float* Erow = E + rowq * Sn;
  for (int i = tloc; i < Sn; i += 128) Es[half][i] = Erow[i];
  __syncthreads();
  float part = Es[half][tloc] + Es[half][tloc + 128] +
               Es[half][tloc + 256] + Es[half][tloc + 384];
  part = wave_reduce_sum(part);
  if (lane == 0) red[wv] = part;
  __syncthreads();
  float scale = 1.f / fmaxf(red[half * 2] + red[half * 2 + 1], 2e-15f);

  // weighted sum: 4 independent accumulators, 4 loads in flight
  const float* ob = h + (size_t)b * Sn * Hn + tloc;
  float a0 = 0.f, a1 = 0.f, a2 = 0.f, a3 = 0.f;
#pragma unroll 4
  for (int k = 0; k < Sn; k += 4) {
    float e0 = Es[half][k],     h0 = ob[(size_t)k * Hn];
    float e1 = Es[half][k + 1], h1 = ob[(size_t)(k + 1) * Hn];
    float e2 = Es[half][k + 2], h2 = ob[(size_t)(k + 2) * Hn];
    float e3 = Es[half][k + 3], h3 = ob[(size_t)(k + 3) * Hn];
    a0 = fmaf(e0, h0, a0);
    a1 = fmaf(e1, h1, a1);
    a2 = fmaf(e2, h2, a2);
    a3 = fmaf(e3, h3, a3);
  }
  float sfv = ((a0 + a1) + (a2 + a3)) * scale;
  sf[rowq * Hn + tloc] = sfv;
  sfs[half][tloc]  = sfv;
  acts[half][tloc] = actions[rowq * Hn + tloc];
  __syncthreads();
  for (int l = 0; l < Ln; ++l) {
    const float* wr = weight + ((size_t)l * Hn + tloc) * Hn;
    float tmp = 0.f;
#pragma unroll 4
    for (int k = 0; k < Hn; k += 4) {
      float4 wv4 = *(const float4*)(wr + k);
      tmp = fmaf(wv4.x, sfs[half][k],     tmp);
      tmp = fmaf(wv4.y, sfs[half][k + 1], tmp);
      tmp = fmaf(wv4.z, sfs[half][k + 2], tmp);
      tmp = fmaf(wv4.w, sfs[half][k + 3], tmp);
    }
    float pa = acts[half][tloc] * tmp;
    pa = wave_reduce_sum(pa);
    if (lane == 0) redl[wv] = pa;
    __syncthreads();
    float tot = redl[half * 2] + redl[half * 2 + 1];
    if (tloc == 0) adv[rowq * Ln + l] = tot + bias[l];
    __syncthreads();
  }
}

// Fused: sem = mean_q sf ; val = Wv.sem+bv ; q = val + adv - mean(adv)
__global__ __launch_bounds__(256) void final2_kernel(
    const float* __restrict__ sf, const float* __restrict__ am,
    const float* __restrict__ Wv, const float* __restrict__ bv,
    const float* __restrict__ adv, float* __restrict__ outq)
{
  __shared__ float red[4];
  int b = blockIdx.x, t = TID;
  float num = 0.f;
  for (int i = 0; i < S2n; ++i) num += am[b * S2n + i];
  float pv = 0.f;
  if (t < Hn) {
    float s = 0.f;
    const float* sb = sf + (size_t)b * S2n * Hn + t;
    for (int q = 0; q < S2n; ++q) s += sb[(size_t)q * Hn];
    pv = Wv[t] * (s / num);
  }
  float val = block_reduce_sum(pv, red) + bv[0];
  const float* advb = adv + (size_t)b * S2n * Ln;
  float pa   = (t < S2n * Ln) ? advb[t] : 0.f;
  float mean = block_reduce_sum(pa, red) / (float)(S2n * Ln);
  for (int i = t; i < S2n * Ln; i += 256)
    outq[(size_t)b * S2n * Ln + i] = val + advb[i] - mean;
}

extern "C" void kernel_launch(void* const* d_in, const int* in_sizes, int n_in,
                              void* d_out, int out_size, void* d_ws, size_t ws_size,
                              hipStream_t stream)
{
  const float* states       = (const float*)d_in[0];
  const float* state_mask   = (const float*)d_in[1];
  const float* actions      = (const float*)d_in[2];
  const float* actions_mask = (const float*)d_in[3];
  const float* adj          = (const float*)d_in[4];
  const float* Wn  = (const float*)d_in[5];
  const float* bn  = (const float*)d_in[6];
  const float* Wu  = (const float*)d_in[7];
  const float* bu  = (const float*)d_in[8];
  const float* Wr  = (const float*)d_in[9];
  const float* br  = (const float*)d_in[10];
  const float* Wt  = (const float*)d_in[11];
  const float* bt  = (const float*)d_in[12];
  const float* Wa1 = (const float*)d_in[13];
  const float* ba1 = (const float*)d_in[14];
  const float* Wa2 = (const float*)d_in[15];
  const float* ba2 = (const float*)d_in[16];
  const float* Wv  = (const float*)d_in[17];
  const float* bvp = (const float*)d_in[18];
  const float* weight = (const float*)d_in[19];
  const float* bias   = (const float*)d_in[20];

  float* ws   = (float*)d_ws;
  float* h    = ws;                   // [8192][128]
  float* g    = ws + (1 << 20);       // [8192][384]
  float* zp   = ws + 4 * (1 << 20);   // [8192][128]
  float* rh   = ws + 5 * (1 << 20);   // [8192][128]
  float* kp   = ws + 6 * (1 << 20);   // [8192][128]
  float* qp   = ws + 7 * (1 << 20);   // [1024][128]
  float* E    = ws + 8 * (1 << 20);   // [16][64][512]
  float* sfb  = ws + 9 * (1 << 20);   // [16][64][128]
  float* adv  = sfb + 262144;         // [16][64][3]
  float* aux  = ws + 10 * (1 << 20);
  float* WtRT = aux;                  // [128][128]
  float* Wa1T = WtRT + 16384;         // [256][128] rows 0..127=TL,128..255=TR
  float* cu   = Wa1T + 32768;
  float* cr   = cu + 128;
  float* ct   = cr + 128;
  short* Bp   = (short*)(ws + 12 * (1 << 20));
  unsigned short* idx = (unsigned short*)(ws + 13 * (1 << 20));
  int* cnts   = (int*)(ws + 14 * (1 << 20));

  prep1<<<2048 + 48, 256, 0, stream>>>(adj, idx, cnts, Wt, Wa1, WtRT, Wa1T);
  combine_pack<<<dim3(128, 3), 128, 0, stream>>>(Wn, Wu, Wr, Wt, bn, Bp,
                                                 cu, cr, ct);

  for (int step = 0; step < 3; ++step) {
    const float* hin = (step == 0) ? states : h;
    gemm_gf<<<dim3(128, 3), 256, 0, stream>>>(hin, Bp, ct, g);
    adj_gate<<<2048, 256, 0, stream>>>(idx, cnts, g, hin,
                                       cu, cr, bu, br, zp, rh);
    int grid = (step == 0) ? 512 + 64 : 512;   // step 0 also computes qp
    gemm_hh<<<grid, 256, 0, stream>>>(
        rh, g, WtRT, bt, zp, hin, h,
        step == 2 ? Wa1T + 16384 : nullptr, kp,
        actions, Wa1T, qp);
  }

  scores_exp_v3<<<dim3(Sn / 32, 2, Bn), 256, 0, stream>>>(
      qp, kp, ba1, Wa2, ba2, actions_mask, state_mask, E);
  fused_fg2<<<512, 256, 0, stream>>>(E, h, actions, weight,
                                     bias, sfb, adv);
  final2_kernel<<<Bn, 256, 0, stream>>>(sfb, actions_mask, Wv, bvp, adv,
                                        (float*)d_out);
}

// Round 24
// 173.252 us; speedup vs baseline: 4.1448x; 1.0310x over previous
//
#include <hip/hip_runtime.h>
#include <math.h>

constexpr int Bn  = 16;
constexpr int Sn  = 512;
constexpr int S2n = 64;
constexpr int Hn  = 128;
constexpr int Ln  = 3;
constexpr int NNZ_CAP = 128;

#define TID ((int)threadIdx.x)

typedef __attribute__((ext_vector_type(8))) short bf16x8;
typedef __attribute__((ext_vector_type(4))) float f32x4;

__device__ inline float wave_reduce_sum(float v) {
#pragma unroll
  for (int off = 32; off > 0; off >>= 1) v += __shfl_xor(v, off, 64);
  return v;
}

__device__ inline float block_reduce_sum(float v, float* red) {
  v = wave_reduce_sum(v);
  int w  = TID >> 6;
  int nw = (int)blockDim.x >> 6;
  if ((TID & 63) == 0) red[w] = v;
  __syncthreads();
  float s = 0.f;
  for (int i = 0; i < nw; ++i) s += red[i];
  __syncthreads();
  return s;
}

__device__ inline float sigm(float x) { return 1.f / (1.f + expf(-x)); }

__device__ inline unsigned short f2bf(float f) {
  unsigned int u = __float_as_uint(f);
  u = (u + 0x7fffu + ((u >> 16) & 1u)) >> 16;
  return (unsigned short)u;
}

// prep_all: bid<2048 adjacency compaction; 2048..2095 transposes;
// 2096..2287 combine+pack (2 (mat,n) units per 256-thread block).
__global__ __launch_bounds__(256) void prep_all(
    const float* __restrict__ adj,
    unsigned short* __restrict__ idx, int* __restrict__ cnts,
    const float* __restrict__ Wt, const float* __restrict__ Wa1,
    float* __restrict__ WtRT, float* __restrict__ Wa1T,
    const float* __restrict__ Wn, const float* __restrict__ Wu,
    const float* __restrict__ Wr, const float* __restrict__ bn,
    short* __restrict__ Bp,
    float* __restrict__ cu, float* __restrict__ cr, float* __restrict__ ct)
{
  __shared__ float t[32][33];
  __shared__ float Ws[2][128];
  __shared__ float bns[128];
  __shared__ float red[4];
  int bid = blockIdx.x;
  int tt = TID;
  int lane = tt & 63, wv = tt >> 6;

  if (bid < 2048) {
    int row = bid * 4 + wv;
    const float* ar = adj + (size_t)row * Sn;
    unsigned short* out = idx + (size_t)row * NNZ_CAP;
    int base = 0;
    for (int j0 = 0; j0 < Sn; j0 += 64) {
      float av = ar[j0 + lane];
      unsigned long long mask = __ballot(av != 0.f);
      int pos = __popcll(mask & ((1ull << lane) - 1ull));
      if (av != 0.f) out[base + pos] = (unsigned short)(j0 + lane);
      base += __popcll(mask);
    }
    if (lane == 0) cnts[row] = base;
    return;
  }
  if (bid < 2096) {
    int flat = bid - 2048;
    const float* src; float* dst; int k0, n0, woff;
    if (flat < 16) { src = Wt;  dst = WtRT; k0 = (flat & 3) * 32; n0 = (flat >> 2) * 32; woff = 128; }
    else { int f2 = flat - 16; src = Wa1; dst = Wa1T; k0 = (f2 & 7) * 32; n0 = (f2 >> 3) * 32; woff = 0; }
    int tx = tt & 31, ty = tt >> 5;
#pragma unroll
    for (int i = 0; i < 32; i += 8)
      t[ty + i][tx] = src[(size_t)(n0 + ty + i) * 256 + woff + k0 + tx];
    __syncthreads();
#pragma unroll
    for (int i = 0; i < 32; i += 8)
      dst[(size_t)(k0 + ty + i) * 128 + n0 + tx] = t[tx][ty + i];
    return;
  }
  int half = tt >> 7, tloc = tt & 127;
  int u = (bid - 2096) * 2 + half;
  int mat = u >> 7, n = u & 127;
  const float* W = (mat == 0) ? Wu : (mat == 1) ? Wr : Wt;
  float* cv = (mat == 0) ? cu : (mat == 1) ? cr : ct;
  Ws[half][tloc] = W[(size_t)n * 256 + tloc];
  if (tt < 128) bns[tt] = bn[tt];
  __syncthreads();
  float acc = 0.f;
#pragma unroll 4
  for (int c = 0; c < 128; ++c)
    acc = fmaf(Wn[(size_t)c * 128 + tloc], Ws[half][c], acc);
  if (mat < 2) acc += W[(size_t)n * 256 + 128 + tloc];
  int k = tloc;
  int id2 = ((mat * 8 + (n >> 4)) * 4 + (k >> 5)) * 512 +
            (((k & 31) >> 3) * 16 + (n & 15)) * 8 + (k & 7);
  Bp[id2] = (short)f2bf(acc);
  float pv = bns[tloc] * Ws[half][tloc];
  pv = wave_reduce_sum(pv);
  if (lane == 0) red[wv] = pv;
  __syncthreads();
  if (tloc == 0) cv[n] = red[half * 2] + red[half * 2 + 1];
}

// MFMA bf16 gemm: g[row][mat*128+n] = h @ G_mat (+ct for mat 2).
// XCD-pinned: bid.x = tt*16 + b.
__global__ __launch_bounds__(256) void gemm_gf(
    const float* __restrict__ h, const short* __restrict__ Bp,
    const float* __restrict__ ctv, float* __restrict__ g)
{
  int w = TID >> 6, l = TID & 63;
  int x = blockIdx.x;
  int b = x & 15, tt = x >> 4;
  int r0 = b * 512 + tt * 64 + w * 16;
  int mat = blockIdx.y;
  const float* abase = h + (size_t)(r0 + (l & 15)) * 128 + (l >> 4) * 8;
  bf16x8 a[4];
#pragma unroll
  for (int kc = 0; kc < 4; ++kc) {
    float4 f0 = *(const float4*)(abase + kc * 32);
    float4 f1 = *(const float4*)(abase + kc * 32 + 4);
    bf16x8 v;
    v[0] = (short)f2bf(f0.x); v[1] = (short)f2bf(f0.y);
    v[2] = (short)f2bf(f0.z); v[3] = (short)f2bf(f0.w);
    v[4] = (short)f2bf(f1.x); v[5] = (short)f2bf(f1.y);
    v[6] = (short)f2bf(f1.z); v[7] = (short)f2bf(f1.w);
    a[kc] = v;
  }
  f32x4 acc[8];
#pragma unroll
  for (int nt = 0; nt < 8; ++nt) acc[nt] = (f32x4){0.f, 0.f, 0.f, 0.f};
  const short* bbase = Bp + (size_t)(mat * 8) * 4 * 512 + l * 8;
#pragma unroll
  for (int nt = 0; nt < 8; ++nt)
#pragma unroll
    for (int kc = 0; kc < 4; ++kc) {
      bf16x8 bb = *(const bf16x8*)(bbase + (nt * 4 + kc) * 512);
      acc[nt] = __builtin_amdgcn_mfma_f32_16x16x32_bf16(a[kc], bb, acc[nt], 0, 0, 0);
    }
  int col0 = l & 15, rb2 = (l >> 4) * 4;
  float* gout = g + (size_t)(r0 + rb2) * 384 + mat * 128 + col0;
#pragma unroll
  for (int nt = 0; nt < 8; ++nt) {
    float cadd = (mat == 2) ? ctv[nt * 16 + col0] : 0.f;
#pragma unroll
    for (int r = 0; r < 4; ++r)
      gout[(size_t)r * 384 + nt * 16] = acc[nt][r] + cadd;
  }
}

// Sparse gather gates, 1 row/wave. XCD-pinned: bid = tl*16 + b. 8-deep ILP.
__global__ __launch_bounds__(256) void adj_gate(
    const unsigned short* __restrict__ idx, const int* __restrict__ cnts,
    const float* __restrict__ g, const float* __restrict__ h,
    const float* __restrict__ cu, const float* __restrict__ cr,
    const float* __restrict__ bu, const float* __restrict__ br,
    float* __restrict__ z, float* __restrict__ rh)
{
  int bid = blockIdx.x;
  int b = bid & 15, tl = bid >> 4;
  int wid = TID >> 6, lane = TID & 63;
  int i = tl * 4 + wid;
  size_t row = (size_t)b * Sn + i;
  int c = (lane < 32) ? 4 * lane : 128 + 4 * (lane - 32);
  const float* gb = g + (size_t)b * Sn * 384 + c;
  const unsigned short* ix = idx + row * NNZ_CAP;
  int cnt = cnts[row];
  float4 acc = {0.f, 0.f, 0.f, 0.f};
  int n = 0;
  for (; n + 8 <= cnt; n += 8) {
    ushort4 ja = *(const ushort4*)(ix + n);
    ushort4 jb = *(const ushort4*)(ix + n + 4);
    float4 x0 = *(const float4*)(gb + (size_t)ja.x * 384);
    float4 x1 = *(const float4*)(gb + (size_t)ja.y * 384);
    float4 x2 = *(const float4*)(gb + (size_t)ja.z * 384);
    float4 x3 = *(const float4*)(gb + (size_t)ja.w * 384);
    float4 x4 = *(const float4*)(gb + (size_t)jb.x * 384);
    float4 x5 = *(const float4*)(gb + (size_t)jb.y * 384);
    float4 x6 = *(const float4*)(gb + (size_t)jb.z * 384);
    float4 x7 = *(const float4*)(gb + (size_t)jb.w * 384);
    acc.x += ((x0.x + x1.x) + (x2.x + x3.x)) + ((x4.x + x5.x) + (x6.x + x7.x));
    acc.y += ((x0.y + x1.y) + (x2.y + x3.y)) + ((x4.y + x5.y) + (x6.y + x7.y));
    acc.z += ((x0.z + x1.z) + (x2.z + x3.z)) + ((x4.z + x5.z) + (x6.z + x7.z));
    acc.w += ((x0.w + x1.w) + (x2.w + x3.w)) + ((x4.w + x5.w) + (x6.w + x7.w));
  }
  for (; n + 4 <= cnt; n += 4) {
    ushort4 jj = *(const ushort4*)(ix + n);
    float4 x0 = *(const float4*)(gb + (size_t)jj.x * 384);
    float4 x1 = *(const float4*)(gb + (size_t)jj.y * 384);
    float4 x2 = *(const float4*)(gb + (size_t)jj.z * 384);
    float4 x3 = *(const float4*)(gb + (size_t)jj.w * 384);
    acc.x += (x0.x + x1.x) + (x2.x + x3.x);
    acc.y += (x0.y + x1.y) + (x2.y + x3.y);
    acc.z += (x0.z + x1.z) + (x2.z + x3.z);
    acc.w += (x0.w + x1.w) + (x2.w + x3.w);
  }
  for (; n < cnt; ++n) {
    int j = ix[n];
    float4 x = *(const float4*)(gb + (size_t)j * 384);
    acc.x += x.x; acc.y += x.y; acc.z += x.z; acc.w += x.w;
  }
  float d = (float)cnt;
  int cc = (lane < 32) ? 4 * lane : 4 * (lane - 32);
  const float* cvp = (lane < 32) ? cu : cr;
  const float* bvp = (lane < 32) ? bu : br;
  float4 cv = *(const float4*)(cvp + cc);
  float4 bv = *(const float4*)(bvp + cc);
  float4 sg;
  sg.x = sigm(acc.x + d * cv.x + bv.x);
  sg.y = sigm(acc.y + d * cv.y + bv.y);
  sg.z = sigm(acc.z + d * cv.z + bv.z);
  sg.w = sigm(acc.w + d * cv.w + bv.w);
  if (lane < 32) {
    *(float4*)(z + row * 128 + cc) = sg;
  } else {
    float4 hv = *(const float4*)(h + row * 128 + cc);
    sg.x *= hv.x; sg.y *= hv.y; sg.z *= hv.z; sg.w *= hv.w;
    *(float4*)(rh + row * 128 + cc) = sg;
  }
}

// h_new = h + z*(tanh(rh@WtRT + g_t + bt) - h); optional kp epilogue.
// bid<512: XCD-pinned tile (b = bid&15, tile = bid>>4). bid>=512: qp gemm.
__global__ __launch_bounds__(256) void gemm_hh(
    const float* __restrict__ rh, const float* __restrict__ g,
    const float* __restrict__ WtRT, const float* __restrict__ bt,
    const float* __restrict__ z, const float* __restrict__ h_in,
    float* __restrict__ h_out,
    const float* __restrict__ WeT, float* __restrict__ e_out,
    const float* __restrict__ qX, const float* __restrict__ qWT,
    float* __restrict__ qY)
{
  __shared__ float Xs[16 * 128];
  int bid = blockIdx.x;
  int t = TID;
  int c4 = (t & 31) * 4;
  int rb = (t >> 5) * 2;

  if (bid >= 512) {
    int r0 = (bid - 512) * 16;
    const float* xsrc = qX + (size_t)r0 * 128;
    for (int i = t; i < 512; i += 256)
      ((float4*)Xs)[i] = ((const float4*)xsrc)[i];
    __syncthreads();
    float acc[2][4] = {};
#pragma unroll 4
    for (int k = 0; k < 128; k += 4) {
      const float* wk = qWT + (size_t)k * 128 + c4;
      float4 w0 = *(const float4*)(wk);
      float4 w1 = *(const float4*)(wk + 128);
      float4 w2 = *(const float4*)(wk + 256);
      float4 w3 = *(const float4*)(wk + 384);
#pragma unroll
      for (int r = 0; r < 2; ++r) {
        float4 x = *(const float4*)&Xs[(rb + r) * 128 + k];
        acc[r][0] = fmaf(x.x, w0.x, acc[r][0]); acc[r][0] = fmaf(x.y, w1.x, acc[r][0]);
        acc[r][0] = fmaf(x.z, w2.x, acc[r][0]); acc[r][0] = fmaf(x.w, w3.x, acc[r][0]);
        acc[r][1] = fmaf(x.x, w0.y, acc[r][1]); acc[r][1] = fmaf(x.y, w1.y, acc[r][1]);
        acc[r][1] = fmaf(x.z, w2.y, acc[r][1]); acc[r][1] = fmaf(x.w, w3.y, acc[r][1]);
        acc[r][2] = fmaf(x.x, w0.z, acc[r][2]); acc[r][2] = fmaf(x.y, w1.z, acc[r][2]);
        acc[r][2] = fmaf(x.z, w2.z, acc[r][2]); acc[r][2] = fmaf(x.w, w3.z, acc[r][2]);
        acc[r][3] = fmaf(x.x, w0.w, acc[r][3]); acc[r][3] = fmaf(x.y, w1.w, acc[r][3]);
        acc[r][3] = fmaf(x.z, w2.w, acc[r][3]); acc[r][3] = fmaf(x.w, w3.w, acc[r][3]);
      }
    }
#pragma unroll
    for (int r = 0; r < 2; ++r) {
      float4 v = {acc[r][0], acc[r][1], acc[r][2], acc[r][3]};
      *(float4*)(qY + (size_t)(r0 + rb + r) * 128 + c4) = v;
    }
    return;
  }

  int b = bid & 15, tile = bid >> 4;
  int r0 = b * 512 + tile * 16;
  const float* xsrc = rh + (size_t)r0 * 128;
  for (int i = t; i < 512; i += 256)
    ((float4*)Xs)[i] = ((const float4*)xsrc)[i];
  __syncthreads();
  float acc[2][4] = {};
#pragma unroll 4
  for (int k = 0; k < 128; k += 4) {
    const float* wk = WtRT + (size_t)k * 128 + c4;
    float4 w0 = *(const float4*)(wk);
    float4 w1 = *(const float4*)(wk + 128);
    float4 w2 = *(const float4*)(wk + 256);
    float4 w3 = *(const float4*)(wk + 384);
#pragma unroll
    for (int r = 0; r < 2; ++r) {
      float4 x = *(const float4*)&Xs[(rb + r) * 128 + k];
      acc[r][0] = fmaf(x.x, w0.x, acc[r][0]); acc[r][0] = fmaf(x.y, w1.x, acc[r][0]);
      acc[r][0] = fmaf(x.z, w2.x, acc[r][0]); acc[r][0] = fmaf(x.w, w3.x, acc[r][0]);
      acc[r][1] = fmaf(x.x, w0.y, acc[r][1]); acc[r][1] = fmaf(x.y, w1.y, acc[r][1]);
      acc[r][1] = fmaf(x.z, w2.y, acc[r][1]); acc[r][1] = fmaf(x.w, w3.y, acc[r][1]);
      acc[r][2] = fmaf(x.x, w0.z, acc[r][2]); acc[r][2] = fmaf(x.y, w1.z, acc[r][2]);
      acc[r][2] = fmaf(x.z, w2.z, acc[r][2]); acc[r][2] = fmaf(x.w, w3.z, acc[r][2]);
      acc[r][3] = fmaf(x.x, w0.w, acc[r][3]); acc[r][3] = fmaf(x.y, w1.w, acc[r][3]);
      acc[r][3] = fmaf(x.z, w2.w, acc[r][3]); acc[r][3] = fmaf(x.w, w3.w, acc[r][3]);
    }
  }
  float4 btv = *(const float4*)(bt + c4);
  float hn[2][4];
#pragma unroll
  for (int r = 0; r < 2; ++r) {
    size_t row = r0 + rb + r;
    float4 gt = *(const float4*)(g + row * 384 + 256 + c4);
    float4 hv = *(const float4*)(h_in + row * 128 + c4);
    float4 zv = *(const float4*)(z + row * 128 + c4);
    hn[r][0] = hv.x + zv.x * (tanhf(acc[r][0] + gt.x + btv.x) - hv.x);
    hn[r][1] = hv.y + zv.y * (tanhf(acc[r][1] + gt.y + btv.y) - hv.y);
    hn[r][2] = hv.z + zv.z * (tanhf(acc[r][2] + gt.z + btv.z) - hv.z);
    hn[r][3] = hv.w + zv.w * (tanhf(acc[r][3] + gt.w + btv.w) - hv.w);
    float4 o = {hn[r][0], hn[r][1], hn[r][2], hn[r][3]};
    *(float4*)(h_out + row * 128 + c4) = o;
  }
  if (WeT) {
    __syncthreads();
#pragma unroll
    for (int r = 0; r < 2; ++r) {
      float4 o = {hn[r][0], hn[r][1], hn[r][2], hn[r][3]};
      *(float4*)&Xs[(rb + r) * 128 + c4] = o;
    }
    __syncthreads();
    float acc2[2][4] = {};
#pragma unroll 4
    for (int k = 0; k < 128; k += 4) {
      const float* wk = WeT + (size_t)k * 128 + c4;
      float4 w0 = *(const float4*)(wk);
      float4 w1 = *(const float4*)(wk + 128);
      float4 w2 = *(const float4*)(wk + 256);
      float4 w3 = *(const float4*)(wk + 384);
#pragma unroll
      for (int r = 0; r < 2; ++r) {
        float4 x = *(const float4*)&Xs[(rb + r) * 128 + k];
        acc2[r][0] = fmaf(x.x, w0.x, acc2[r][0]); acc2[r][0] = fmaf(x.y, w1.x, acc2[r][0]);
        acc2[r][0] = fmaf(x.z, w2.x, acc2[r][0]); acc2[r][0] = fmaf(x.w, w3.x, acc2[r][0]);
        acc2[r][1] = fmaf(x.x, w0.y, acc2[r][1]); acc2[r][1] = fmaf(x.y, w1.y, acc2[r][1]);
        acc2[r][1] = fmaf(x.z, w2.y, acc2[r][1]); acc2[r][1] = fmaf(x.w, w3.y, acc2[r][1]);
        acc2[r][2] = fmaf(x.x, w0.z, acc2[r][2]); acc2[r][2] = fmaf(x.y, w1.z, acc2[r][2]);
        acc2[r][2] = fmaf(x.z, w2.z, acc2[r][2]); acc2[r][2] = fmaf(x.w, w3.z, acc2[r][2]);
        acc2[r][3] = fmaf(x.x, w0.w, acc2[r][3]); acc2[r][3] = fmaf(x.y, w1.w, acc2[r][3]);
        acc2[r][3] = fmaf(x.z, w2.w, acc2[r][3]); acc2[r][3] = fmaf(x.w, w3.w, acc2[r][3]);
      }
    }
#pragma unroll
    for (int r = 0; r < 2; ++r) {
      float4 v = {acc2[r][0], acc2[r][1], acc2[r][2], acc2[r][3]};
      *(float4*)(e_out + (size_t)(r0 + rb + r) * 128 + c4) = v;
    }
  }
}

// E[b,q,k] = mask ? exp(relu(Wa2 . relu(qp[b,q]+kp[b,k]+ba1) + ba2)) : 0
__global__ __launch_bounds__(256) void scores_exp_v3(
    const float* __restrict__ qp, const float* __restrict__ kp,
    const float* __restrict__ ba1, const float* __restrict__ Wa2,
    const float* __restrict__ ba2, const float* __restrict__ am,
    const float* __restrict__ smk, float* __restrict__ E)
{
  constexpr int KT = 32, QT = 32;
  __shared__ float qs[QT][132];
  __shared__ float ks[KT][132];
  __shared__ float w2s[128];
  __shared__ float es[QT][33];
  int b = blockIdx.z, kt = blockIdx.x * KT, qt = blockIdx.y * QT;
  const float* qsrc = qp + ((size_t)b * S2n + qt) * Hn;
  for (int f = TID; f < QT * 32; f += 256) {
    int q = f >> 5, g = f & 31;
    float4 v  = ((const float4*)qsrc)[f];
    float4 bb = ((const float4*)ba1)[g];
    v.x += bb.x; v.y += bb.y; v.z += bb.z; v.w += bb.w;
    *(float4*)&qs[q][4 * g] = v;
  }
  const float* ksrc = kp + ((size_t)b * Sn + kt) * Hn;
  for (int f = TID; f < KT * 32; f += 256) {
    int k = f >> 5, g = f & 31;
    *(float4*)&ks[k][4 * g] = ((const float4*)ksrc)[f];
  }
  if (TID < 128) w2s[TID] = Wa2[TID];
  __syncthreads();
  const int q0 = (TID & 15) * 2;
  const int k0 = (TID >> 4) * 2;
  float acc[2][2] = {};
#pragma unroll 4
  for (int h = 0; h < 128; ++h) {
    float w  = w2s[h];
    float kv0 = ks[k0][h], kv1 = ks[k0 + 1][h];
    float qv0 = qs[q0][h], qv1 = qs[q0 + 1][h];
    acc[0][0] = fmaf(fmaxf(qv0 + kv0, 0.f), w, acc[0][0]);
    acc[0][1] = fmaf(fmaxf(qv0 + kv1, 0.f), w, acc[0][1]);
    acc[1][0] = fmaf(fmaxf(qv1 + kv0, 0.f), w, acc[1][0]);
    acc[1][1] = fmaf(fmaxf(qv1 + kv1, 0.f), w, acc[1][1]);
  }
  float b2 = ba2[0];
#pragma unroll
  for (int i = 0; i < 2; ++i) {
    float amq = am[b * S2n + qt + q0 + i];
#pragma unroll
    for (int j = 0; j < 2; ++j) {
      float m = amq * smk[b * Sn + kt + k0 + j];
      float s = fmaxf(acc[i][j] + b2, 0.f);
      es[q0 + i][k0 + j] = (m > 0.f) ? expf(s) : 0.f;
    }
  }
  __syncthreads();
  float* Eb = E + ((size_t)b * S2n + qt) * Sn + kt;
  for (int f = TID; f < QT * KT; f += 256) {
    int q = f >> 5, kin = f & 31;
    Eb[(size_t)q * Sn + kin] = es[q][kin];
  }
}

// Fused attn weighted sum + adv, v3: flat XCD-pinned grid (b = bid&15),
// 4 independent k-chain accumulators; single-pass 3-way adv (1 barrier).
__global__ __launch_bounds__(256) void fused_fg2(
    const float* __restrict__ E, const float* __restrict__ h,
    const float* __restrict__ actions, const float* __restrict__ weight,
    const float* __restrict__ bias, float* __restrict__ sf,
    float* __restrict__ adv)
{
  __shared__ float Es[2][512];
  __shared__ float red[4];
  __shared__ float sfs[2][128];
  __shared__ float acts[2][128];
  __shared__ float redl[12];
  int bid = blockIdx.x;
  int b = bid & 15, qpair = bid >> 4;
  int t = TID, lane = t & 63, wv = t >> 6;
  int half = t >> 7, tloc = t & 127;
  int q = qpair * 2 + half;
  size_t rowq = (size_t)b * S2n + q;
  const float* Erow = E + rowq * Sn;
  for (int i = tloc; i < Sn; i += 128) Es[half][i] = Erow[i];
  __syncthreads();
  float part = Es[half][tloc] + Es[half][tloc + 128] +
               Es[half][tloc + 256] + Es[half][tloc + 384];
  part = wave_reduce_sum(part);
  if (lane == 0) red[wv] = part;
  __syncthreads();
  float scale = 1.f / fmaxf(red[half * 2] + red[half * 2 + 1], 2e-15f);

  const float* ob = h + (size_t)b * Sn * Hn + tloc;
  float a0 = 0.f, a1 = 0.f, a2 = 0.f, a3 = 0.f;
#pragma unroll 4
  for (int k = 0; k < Sn; k += 4) {
    float e0 = Es[half][k],     h0 = ob[(size_t)k * Hn];
    float e1 = Es[half][k + 1], h1 = ob[(size_t)(k + 1) * Hn];
    float e2 = Es[half][k + 2], h2 = ob[(size_t)(k + 2) * Hn];
    float e3 = Es[half][k + 3], h3 = ob[(size_t)(k + 3) * Hn];
    a0 = fmaf(e0, h0, a0);
    a1 = fmaf(e1, h1, a1);
    a2 = fmaf(e2, h2, a2);
    a3 = fmaf(e3, h3, a3);
  }
  float sfv = ((a0 + a1) + (a2 + a3)) * scale;
  sf[rowq * Hn + tloc] = sfv;
  sfs[half][tloc]  = sfv;
  acts[half][tloc] = actions[rowq * Hn + tloc];
  __syncthreads();

  float tmp[3] = {0.f, 0.f, 0.f};
#pragma unroll
  for (int l = 0; l < Ln; ++l) {
    const float* wr = weight + ((size_t)l * Hn + tloc) * Hn;
#pragma unroll 4
    for (int k = 0; k < Hn; k += 4) {
      float4 wv4 = *(const float4*)(wr + k);
      tmp[l] = fmaf(wv4.x, sfs[half][k],     tmp[l]);
      tmp[l] = fmaf(wv4.y, sfs[half][k + 1], tmp[l]);
      tmp[l] = fmaf(wv4.z, sfs[half][k + 2], tmp[l]);
      tmp[l] = fmaf(wv4.w, sfs[half][k + 3], tmp[l]);
    }
  }
  float av = acts[half][tloc];
  float p0 = wave_reduce_sum(av * tmp[0]);
  float p1 = wave_reduce_sum(av * tmp[1]);
  float p2 = wave_reduce_sum(av * tmp[2]);
  if (lane == 0) {
    redl[wv * 3 + 0] = p0;
    redl[wv * 3 + 1] = p1;
    redl[wv * 3 + 2] = p2;
  }
  __syncthreads();
  if (tloc < Ln) {
    float tot = redl[(half * 2) * 3 + tloc] + redl[(half * 2 + 1) * 3 + tloc];
    adv[rowq * Ln + tloc] = tot + bias[tloc];
  }
}

// Fused: sem = mean_q sf ; val = Wv.sem+bv ; q = val + adv - mean(adv)
__global__ __launch_bounds__(256) void final2_kernel(
    const float* __restrict__ sf, const float* __restrict__ am,
    const float* __restrict__ Wv, const float* __restrict__ bv,
    const float* __restrict__ adv, float* __restrict__ outq)
{
  __shared__ float red[4];
  int b = blockIdx.x, t = TID;
  float num = 0.f;
  for (int i = 0; i < S2n; ++i) num += am[b * S2n + i];
  float pv = 0.f;
  if (t < Hn) {
    float s = 0.f;
    const float* sb = sf + (size_t)b * S2n * Hn + t;
    for (int q = 0; q < S2n; ++q) s += sb[(size_t)q * Hn];
    pv = Wv[t] * (s / num);
  }
  float val = block_reduce_sum(pv, red) + bv[0];
  const float* advb = adv + (size_t)b * S2n * Ln;
  float pa   = (t < S2n * Ln) ? advb[t] : 0.f;
  float mean = block_reduce_sum(pa, red) / (float)(S2n * Ln);
  for (int i = t; i < S2n * Ln; i += 256)
    outq[(size_t)b * S2n * Ln + i] = val + advb[i] - mean;
}

extern "C" void kernel_launch(void* const* d_in, const int* in_sizes, int n_in,
                              void* d_out, int out_size, void* d_ws, size_t ws_size,
                              hipStream_t stream)
{
  const float* states       = (const float*)d_in[0];
  const float* state_mask   = (const float*)d_in[1];
  const float* actions      = (const float*)d_in[2];
  const float* actions_mask = (const float*)d_in[3];
  const float* adj          = (const float*)d_in[4];
  const float* Wn  = (const float*)d_in[5];
  const float* bn  = (const float*)d_in[6];
  const float* Wu  = (const float*)d_in[7];
  const float* bu  = (const float*)d_in[8];
  const float* Wr  = (const float*)d_in[9];
  const float* br  = (const float*)d_in[10];
  const float* Wt  = (const float*)d_in[11];
  const float* bt  = (const float*)d_in[12];
  const float* Wa1 = (const float*)d_in[13];
  const float* ba1 = (const float*)d_in[14];
  const float* Wa2 = (const float*)d_in[15];
  const float* ba2 = (const float*)d_in[16];
  const float* Wv  = (const float*)d_in[17];
  const float* bvp = (const float*)d_in[18];
  const float* weight = (const float*)d_in[19];
  const float* bias   = (const float*)d_in[20];

  float* ws   = (float*)d_ws;
  float* h    = ws;                   // [8192][128]
  float* g    = ws + (1 << 20);       // [8192][384]
  float* zp   = ws + 4 * (1 << 20);   // [8192][128]
  float* rh   = ws + 5 * (1 << 20);   // [8192][128]
  float* kp   = ws + 6 * (1 << 20);   // [8192][128]
  float* qp   = ws + 7 * (1 << 20);   // [1024][128]
  float* E    = ws + 8 * (1 << 20);   // [16][64][512]
  float* sfb  = ws + 9 * (1 << 20);   // [16][64][128]
  float* adv  = sfb + 262144;         // [16][64][3]
  float* aux  = ws + 10 * (1 << 20);
  float* WtRT = aux;                  // [128][128]
  float* Wa1T = WtRT + 16384;         // [256][128] rows 0..127=TL,128..255=TR
  float* cu   = Wa1T + 32768;
  float* cr   = cu + 128;
  float* ct   = cr + 128;
  short* Bp   = (short*)(ws + 12 * (1 << 20));
  unsigned short* idx = (unsigned short*)(ws + 13 * (1 << 20));
  int* cnts   = (int*)(ws + 14 * (1 << 20));

  prep_all<<<2048 + 48 + 192, 256, 0, stream>>>(
      adj, idx, cnts, Wt, Wa1, WtRT, Wa1T,
      Wn, Wu, Wr, bn, Bp, cu, cr, ct);

  for (int step = 0; step < 3; ++step) {
    const float* hin = (step == 0) ? states : h;
    gemm_gf<<<dim3(128, 3), 256, 0, stream>>>(hin, Bp, ct, g);
    adj_gate<<<2048, 256, 0, stream>>>(idx, cnts, g, hin,
                                       cu, cr, bu, br, zp, rh);
    int grid = (step == 0) ? 512 + 64 : 512;   // step 0 also computes qp
    gemm_hh<<<grid, 256, 0, stream>>>(
        rh, g, WtRT, bt, zp, hin, h,
        step == 2 ? Wa1T + 16384 : nullptr, kp,
        actions, Wa1T, qp);
  }

  scores_exp_v3<<<dim3(Sn / 32, 2, Bn), 256, 0, stream>>>(
      qp, kp, ba1, Wa2, ba2, actions_mask, state_mask, E);
  fused_fg2<<<512, 256, 0, stream>>>(E, h, actions, weight,
                                     bias, sfb, adv);
  final2_kernel<<<Bn, 256, 0, stream>>>(sfb, actions_mask, Wv, bvp, adv,
                                        (float*)d_out);
}